// Round 2
// baseline (3342.127 us; speedup 1.0000x reference)
//
#include <hip/hip_runtime.h>
#include <hip/hip_bf16.h>
#include <math.h>

typedef __bf16 bf16;
typedef bf16 bf16x8 __attribute__((ext_vector_type(8)));
typedef bf16 bf16x4 __attribute__((ext_vector_type(4)));
typedef float f32x4 __attribute__((ext_vector_type(4)));

#define BQ 32
#define TT 197
#define DD 768
#define HH 12
#define FF 3072
#define LL 12
#define TP 224
#define MR 6304   // B*T
#define MP 6400   // padded to 50*128
#define MQ 75648  // B*T*H rows for qkv gemm (591*128)
#define KST 72    // K LDS row stride (elements)
#define PST 232   // P / Vt LDS row stride (elements)

typedef __attribute__((address_space(1))) const void gv_t;
typedef __attribute__((address_space(3))) void lv_t;

__device__ __forceinline__ void gld16(const void* g, void* l) {
    __builtin_amdgcn_global_load_lds((gv_t*)g, (lv_t*)l, 16, 0, 0);
}

__device__ __forceinline__ f32x4 mfma16(bf16x8 a, bf16x8 b, f32x4 c) {
    return __builtin_amdgcn_mfma_f32_16x16x32_bf16(a, b, c, 0, 0, 0);
}

// bijective XCD swizzle (m204): consecutive wgid stay on one XCD
__device__ __forceinline__ int xcd_swz(int bid, int nwg) {
    int q = nwg >> 3, r = nwg & 7;
    int xcd = bid & 7, pos = bid >> 3;
    int base = (xcd < r) ? xcd * (q + 1) : r * (q + 1) + (xcd - r) * q;
    return base + pos;
}

// ---------------------------------------------------------------------------
// Generic C = A(M,K) @ W(N,K)^T + bias GEMM, 128x128 tile, BK=64, 4 waves.
// 1-D grid = gx*gy*SPLITK, XCD-swizzled, bx fastest (blocks sharing A-tile
// are consecutive -> same XCD L2).
// EPI 0: patch-embed epilogue -> h rows (b*197+1+n) += pos_enc  (fp32 write)
// EPI 1: exact GELU -> bf16 out (stride N)
// EPI 2: residual atomicAdd into fp32 out (stride 768), rows < MR only;
//        bias added by split 0 only.
// ---------------------------------------------------------------------------
template <int EPI, int SPLITK>
__global__ __launch_bounds__(256, 2)
void gemm_bt(const bf16* __restrict__ A, const bf16* __restrict__ W,
             const float* __restrict__ bias, int K, int N,
             float* __restrict__ outF, bf16* __restrict__ outB,
             const float* __restrict__ pos, int gx, int gy) {
    __shared__ bf16 As[128 * 64];
    __shared__ bf16 Bs[128 * 64];
    const int tid = threadIdx.x;
    const int lane = tid & 63, wave = tid >> 6;
    const int wm = wave >> 1, wn = wave & 1;

    const int wgid = xcd_swz(blockIdx.x, gridDim.x);
    const int ks   = (SPLITK > 1) ? wgid / (gx * gy) : 0;
    const int rem  = (SPLITK > 1) ? wgid % (gx * gy) : wgid;
    const int bx = rem % gx, by = rem / gx;
    const int m0 = by * 128, n0 = bx * 128;

    const int kb = K / SPLITK;
    const int k0 = ks * kb, k1 = k0 + kb;

    f32x4 acc[4][4] = {};
    const bf16* Ab = A + (size_t)m0 * K;
    const bf16* Wb = W + (size_t)n0 * K;

    for (int kt = k0; kt < k1; kt += 64) {
#pragma unroll
        for (int i = 0; i < 4; i++) {
            int idx = i * 256 + tid;
            int row = idx >> 3, cb = idx & 7;
            gld16(Ab + (size_t)row * K + kt + cb * 8, As + idx * 8);
            gld16(Wb + (size_t)row * K + kt + cb * 8, Bs + idx * 8);
        }
        __syncthreads();
        bf16x8 af[4][2], bfr[4][2];
#pragma unroll
        for (int f = 0; f < 4; f++) {
            int ra = (wm * 64 + f * 16 + (lane & 15)) * 64 + ((lane >> 4) * 8);
            af[f][0] = *(const bf16x8*)(As + ra);
            af[f][1] = *(const bf16x8*)(As + ra + 32);
            int rb = (wn * 64 + f * 16 + (lane & 15)) * 64 + ((lane >> 4) * 8);
            bfr[f][0] = *(const bf16x8*)(Bs + rb);
            bfr[f][1] = *(const bf16x8*)(Bs + rb + 32);
        }
#pragma unroll
        for (int kh = 0; kh < 2; kh++)
#pragma unroll
            for (int mf = 0; mf < 4; mf++)
#pragma unroll
                for (int nf = 0; nf < 4; nf++)
                    acc[mf][nf] = mfma16(af[mf][kh], bfr[nf][kh], acc[mf][nf]);
        __syncthreads();
    }

    const int r0 = m0 + wm * 64, c0 = n0 + wn * 64;
#pragma unroll
    for (int mf = 0; mf < 4; mf++) {
#pragma unroll
        for (int j = 0; j < 4; j++) {
            int row = r0 + mf * 16 + ((lane >> 4) * 4) + j;
            int pb = 0, pn = 0;
            if (EPI == 0) { pb = row / 196; pn = row - pb * 196; }
#pragma unroll
            for (int nf = 0; nf < 4; nf++) {
                int col = c0 + nf * 16 + (lane & 15);
                float v = acc[mf][nf][j];
                if (EPI == 0) {
                    v += bias[col];
                    float pv = pos[(size_t)(1 + pn) * DD + col];
                    outF[(size_t)(pb * TT + 1 + pn) * DD + col] = v + pv;
                } else if (EPI == 1) {
                    v += bias[col];
                    float g = 0.5f * v * (1.0f + erff(v * 0.70710678118654752f));
                    outB[(size_t)row * N + col] = (bf16)g;
                } else {
                    if (ks == 0) v += bias[col];
                    if (row < MR) atomicAdd(&outF[(size_t)row * DD + col], v);
                }
            }
        }
    }
}

// ---------------------------------------------------------------------------
// QKV: A = hn viewed as (B*T*H, 64) contiguous (since D = H*64).
// C (MQ,192) = A @ qkv_w(192,64)^T + qkv_b, scattered to Q/K/V (B*H, 224, 64)
// ---------------------------------------------------------------------------
__global__ __launch_bounds__(256, 2)
void qkv_kernel(const bf16* __restrict__ hn, const bf16* __restrict__ qw,
                const float* __restrict__ qb, bf16* __restrict__ Q,
                bf16* __restrict__ Kb, bf16* __restrict__ Vb) {
    __shared__ bf16 Asm[128 * 64];
    __shared__ bf16 Wsm[192 * 64];
    const int tid = threadIdx.x, lane = tid & 63, wave = tid >> 6;
    const size_t base = (size_t)blockIdx.x * (128 * 64);
#pragma unroll
    for (int i = 0; i < 4; i++) { int idx = i * 256 + tid; gld16(hn + base + idx * 8, Asm + idx * 8); }
#pragma unroll
    for (int i = 0; i < 6; i++) { int idx = i * 256 + tid; gld16(qw + idx * 8, Wsm + idx * 8); }
    __syncthreads();

    bf16x8 af[2][2];
#pragma unroll
    for (int mf = 0; mf < 2; mf++) {
        int ra = (wave * 32 + mf * 16 + (lane & 15)) * 64 + (lane >> 4) * 8;
        af[mf][0] = *(const bf16x8*)(Asm + ra);
        af[mf][1] = *(const bf16x8*)(Asm + ra + 32);
    }
    f32x4 acc[2][12] = {};
#pragma unroll
    for (int nf = 0; nf < 12; nf++) {
        int rb = (nf * 16 + (lane & 15)) * 64 + (lane >> 4) * 8;
        bf16x8 b0 = *(const bf16x8*)(Wsm + rb);
        bf16x8 b1 = *(const bf16x8*)(Wsm + rb + 32);
#pragma unroll
        for (int mf = 0; mf < 2; mf++) {
            acc[mf][nf] = mfma16(af[mf][0], b0, acc[mf][nf]);
            acc[mf][nf] = mfma16(af[mf][1], b1, acc[mf][nf]);
        }
    }
    const int r0 = blockIdx.x * 128 + wave * 32;
#pragma unroll
    for (int mf = 0; mf < 2; mf++)
#pragma unroll
        for (int j = 0; j < 4; j++) {
            int r = r0 + mf * 16 + (lane >> 4) * 4 + j;
            int bt = r / 12, hh = r - bt * 12;
            int b = bt / 197, t = bt - b * 197;
            size_t dbase = ((size_t)(b * HH + hh) * TP + t) * 64;
#pragma unroll
            for (int nf = 0; nf < 12; nf++) {
                int col = nf * 16 + (lane & 15);
                float v = acc[mf][nf][j] + qb[col];
                int sel = nf >> 2, e = col & 63;
                bf16* dst = (sel == 0) ? Q : (sel == 1 ? Kb : Vb);
                dst[dbase + e] = (bf16)v;
            }
        }
}

// ---------------------------------------------------------------------------
// Fused attention per (b,h): scores = QK^T*0.125 (masked >=197), softmax,
// O = P@V, h += O (residual). K in LDS [224][72], V transposed [64][232],
// P per-wave [16][232].
// ---------------------------------------------------------------------------
__global__ __launch_bounds__(256, 1)
void attn_kernel(const bf16* __restrict__ Q, const bf16* __restrict__ Kg,
                 const bf16* __restrict__ Vg, float* __restrict__ h) {
    __shared__ bf16 Ks[TP * KST];
    __shared__ bf16 Vt[64 * PST];
    __shared__ bf16 Pw[4 * 16 * PST];
    const int tid = threadIdx.x, lane = tid & 63, wave = tid >> 6;
    const int bh = blockIdx.x;
    const int b = bh / HH, hh = bh - b * HH;
    const bf16* Kp = Kg + (size_t)bh * TP * 64;
    const bf16* Vp = Vg + (size_t)bh * TP * 64;
    const bf16* Qp = Q + (size_t)bh * TP * 64;

#pragma unroll
    for (int i = 0; i < 7; i++) {
        int idx = i * 256 + tid;
        int row = idx >> 3, cb = idx & 7;
        bf16x8 kv = *(const bf16x8*)(Kp + idx * 8);
        *(bf16x8*)(Ks + row * KST + cb * 8) = kv;
        bf16x8 vv = *(const bf16x8*)(Vp + idx * 8);
#pragma unroll
        for (int j = 0; j < 8; j++) Vt[(cb * 8 + j) * PST + row] = vv[j];
    }
    __syncthreads();

    bf16* Pm = Pw + wave * 16 * PST;
    for (int ch = wave; ch < 13; ch += 4) {
        const int q0 = ch * 16;
        const bf16* qp = Qp + (q0 + (lane & 15)) * 64 + (lane >> 4) * 8;
        bf16x8 aq0 = *(const bf16x8*)qp;
        bf16x8 aq1 = *(const bf16x8*)(qp + 32);
        f32x4 s[14] = {};
#pragma unroll
        for (int nf = 0; nf < 14; nf++) {
            int rb = (nf * 16 + (lane & 15)) * KST + (lane >> 4) * 8;
            bf16x8 b0 = *(const bf16x8*)(Ks + rb);
            bf16x8 b1 = *(const bf16x8*)(Ks + rb + 32);
            s[nf] = mfma16(aq0, b0, s[nf]);
            s[nf] = mfma16(aq1, b1, s[nf]);
        }
        const int colbase = lane & 15;
#pragma unroll
        for (int j = 0; j < 4; j++) {
            float pv[14];
            float m = -1e30f;
#pragma unroll
            for (int nf = 0; nf < 14; nf++) {
                int col = nf * 16 + colbase;
                float v = s[nf][j] * 0.125f;
                v = (col < TT) ? v : -1e30f;
                pv[nf] = v;
                m = fmaxf(m, v);
            }
#pragma unroll
            for (int dd = 1; dd < 16; dd <<= 1) m = fmaxf(m, __shfl_xor(m, dd));
            float sum = 0.0f;
#pragma unroll
            for (int nf = 0; nf < 14; nf++) { float e = __expf(pv[nf] - m); pv[nf] = e; sum += e; }
#pragma unroll
            for (int dd = 1; dd < 16; dd <<= 1) sum += __shfl_xor(sum, dd);
            float inv = 1.0f / sum;
            int pr = (lane >> 4) * 4 + j;
#pragma unroll
            for (int nf = 0; nf < 14; nf++)
                Pm[pr * PST + nf * 16 + colbase] = (bf16)(pv[nf] * inv);
        }
        asm volatile("s_waitcnt lgkmcnt(0)" ::: "memory");
        f32x4 o[4] = {};
#pragma unroll
        for (int ks = 0; ks < 7; ks++) {
            bf16x8 pa = *(const bf16x8*)(Pm + (lane & 15) * PST + ks * 32 + (lane >> 4) * 8);
#pragma unroll
            for (int nf = 0; nf < 4; nf++) {
                bf16x8 bv = *(const bf16x8*)(Vt + (nf * 16 + (lane & 15)) * PST + ks * 32 + (lane >> 4) * 8);
                o[nf] = mfma16(pa, bv, o[nf]);
            }
        }
#pragma unroll
        for (int nf = 0; nf < 4; nf++)
#pragma unroll
            for (int j = 0; j < 4; j++) {
                int qr = q0 + (lane >> 4) * 4 + j;
                if (qr < TT) {
                    int d = nf * 16 + (lane & 15);
                    h[(size_t)(b * TT + qr) * DD + hh * 64 + d] += o[nf][j];
                }
            }
    }
}

// ---------------------------------------------------------------------------
// LayerNorm, one row per wave (4 rows/block), fp32 in -> bf16 out
// ---------------------------------------------------------------------------
__global__ void ln_kernel(const float* __restrict__ h, const float* __restrict__ g,
                          const float* __restrict__ bt, bf16* __restrict__ hn) {
    const int lane = threadIdx.x & 63, wave = threadIdx.x >> 6;
    const int row = blockIdx.x * 4 + wave;
    const float* x = h + (size_t)row * DD;
    float4 a[3];
#pragma unroll
    for (int i = 0; i < 3; i++) a[i] = ((const float4*)x)[lane + i * 64];
    float sum = 0.0f;
#pragma unroll
    for (int i = 0; i < 3; i++) sum += a[i].x + a[i].y + a[i].z + a[i].w;
#pragma unroll
    for (int dd = 1; dd < 64; dd <<= 1) sum += __shfl_xor(sum, dd);
    const float mu = sum * (1.0f / 768.0f);
    float sq = 0.0f;
#pragma unroll
    for (int i = 0; i < 3; i++) {
        float dx = a[i].x - mu, dy = a[i].y - mu, dz = a[i].z - mu, dw = a[i].w - mu;
        sq += dx * dx + dy * dy + dz * dz + dw * dw;
    }
#pragma unroll
    for (int dd = 1; dd < 64; dd <<= 1) sq += __shfl_xor(sq, dd);
    const float is = rsqrtf(sq * (1.0f / 768.0f) + 1e-5f);
#pragma unroll
    for (int i = 0; i < 3; i++) {
        int c4 = lane + i * 64;
        float4 gg = ((const float4*)g)[c4];
        float4 bb = ((const float4*)bt)[c4];
        bf16x4 o;
        o[0] = (bf16)((a[i].x - mu) * is * gg.x + bb.x);
        o[1] = (bf16)((a[i].y - mu) * is * gg.y + bb.y);
        o[2] = (bf16)((a[i].z - mu) * is * gg.z + bb.z);
        o[3] = (bf16)((a[i].w - mu) * is * gg.w + bb.w);
        ((bf16x4*)(hn + (size_t)row * DD))[c4] = o;
    }
}

// ---------------------------------------------------------------------------
__global__ void patch_extract(const float* __restrict__ x, bf16* __restrict__ p) {
    int idx = blockIdx.x * 256 + threadIdx.x;
    if (idx >= 6272 * 768) return;
    int k = idx % 768, row = idx / 768;
    int c = k % 3, pc = (k / 3) % 16, pr = k / 48;
    int b = row / 196, n = row - b * 196;
    int hp = n / 14, wp = n - hp * 14;
    p[idx] = (bf16)x[((size_t)(b * 3 + c) * 224 + hp * 16 + pr) * 224 + wp * 16 + pc];
}

__global__ void cast_bf16(const float* __restrict__ in, bf16* __restrict__ out, int n4) {
    int i = blockIdx.x * 256 + threadIdx.x;
    int stride = gridDim.x * 256;
    for (; i < n4; i += stride) {
        float4 v = ((const float4*)in)[i];
        bf16x4 o;
        o[0] = (bf16)v.x; o[1] = (bf16)v.y; o[2] = (bf16)v.z; o[3] = (bf16)v.w;
        ((bf16x4*)out)[i] = o;
    }
}

__global__ void cls_init(const float* __restrict__ cls, const float* __restrict__ pos,
                         float* __restrict__ h) {
    int i = blockIdx.x * 256 + threadIdx.x;
    if (i >= BQ * DD) return;
    int b = i / DD, c = i - b * DD;
    h[(size_t)(b * TT) * DD + c] = cls[c] + pos[c];
}

__global__ void head_kernel(const float* __restrict__ h, const float* __restrict__ hw,
                            const float* __restrict__ hb, float* __restrict__ out) {
    __shared__ float xr[DD];
    const int b = blockIdx.y;
    const int n = blockIdx.x * 256 + threadIdx.x;
    for (int i = threadIdx.x; i < DD; i += 256) xr[i] = h[(size_t)(b * TT) * DD + i];
    __syncthreads();
    if (n < 1000) {
        float s = hb[n];
        const float4* w = (const float4*)(hw + (size_t)n * DD);
        float acc = 0.0f;
#pragma unroll 4
        for (int k = 0; k < DD / 4; k++) {
            float4 wv = w[k];
            float4 xv = ((const float4*)xr)[k];
            acc += wv.x * xv.x + wv.y * xv.y + wv.z * xv.z + wv.w * xv.w;
        }
        out[b * 1000 + n] = s + acc;
    }
}

// ---------------------------------------------------------------------------
extern "C" void kernel_launch(void* const* d_in, const int* in_sizes, int n_in,
                              void* d_out, int out_size, void* d_ws, size_t ws_size,
                              hipStream_t stream) {
    const float* x       = (const float*)d_in[0];
    const float* patch_w = (const float*)d_in[1];
    const float* patch_b = (const float*)d_in[2];
    const float* pos_enc = (const float*)d_in[3];
    const float* cls_tok = (const float*)d_in[4];
    const float* qkv_w   = (const float*)d_in[5];
    const float* qkv_b   = (const float*)d_in[6];
    const float* ln_g    = (const float*)d_in[7];
    const float* ln_b    = (const float*)d_in[8];
    const float* w1      = (const float*)d_in[9];
    const float* b1      = (const float*)d_in[10];
    const float* w2      = (const float*)d_in[11];
    const float* b2      = (const float*)d_in[12];
    const float* head_w  = (const float*)d_in[13];
    const float* head_b  = (const float*)d_in[14];

    char* wp = (char*)d_ws;
    auto carve = [&](size_t bytes) {
        char* r = wp;
        wp += (bytes + 255) & ~(size_t)255;
        return r;
    };
    float* h  = (float*)carve((size_t)MP * DD * 4);
    bf16* hn  = (bf16*)carve((size_t)MP * DD * 2);
    bf16* u   = (bf16*)carve((size_t)MP * FF * 2);
    bf16* qs  = (bf16*)carve((size_t)BQ * HH * TP * 64 * 2);
    bf16* ks  = (bf16*)carve((size_t)BQ * HH * TP * 64 * 2);
    bf16* vs  = (bf16*)carve((size_t)BQ * HH * TP * 64 * 2);
    bf16* p   = (bf16*)carve((size_t)6272 * DD * 2);
    bf16* pwb = (bf16*)carve((size_t)DD * DD * 2);
    bf16* qwb = (bf16*)carve((size_t)LL * 192 * 64 * 2);

    // precast-all path needs 2 * L*F*D bf16; fall back to per-layer buffers
    const size_t wfull = (size_t)LL * FF * DD * 2;
    const size_t base_used = (size_t)(wp - (char*)d_ws);
    const bool precast = (base_used + 2 * (wfull + 256)) <= ws_size;
    bf16* w1b = (bf16*)carve(precast ? wfull : (size_t)FF * DD * 2);
    bf16* w2b = (bf16*)carve(precast ? wfull : (size_t)DD * FF * 2);

    cast_bf16<<<512, 256, 0, stream>>>(patch_w, pwb, (DD * DD) / 4);
    cast_bf16<<<144, 256, 0, stream>>>(qkv_w, qwb, (LL * 192 * 64) / 4);
    if (precast) {
        cast_bf16<<<4096, 256, 0, stream>>>(w1, w1b, (LL * FF * DD) / 4);
        cast_bf16<<<4096, 256, 0, stream>>>(w2, w2b, (LL * FF * DD) / 4);
    }
    patch_extract<<<18816, 256, 0, stream>>>(x, p);
    cls_init<<<96, 256, 0, stream>>>(cls_tok, pos_enc, h);
    gemm_bt<0, 1><<<294, 256, 0, stream>>>(p, pwb, patch_b, 768, 768, h, nullptr,
                                           pos_enc, 6, 49);

    for (int i = 0; i < LL; i++) {
        const bf16* w1i = precast ? (w1b + (size_t)i * FF * DD) : w1b;
        const bf16* w2i = precast ? (w2b + (size_t)i * FF * DD) : w2b;

        ln_kernel<<<MP / 4, 256, 0, stream>>>(h, ln_g + i * DD, ln_b + i * DD, hn);
        qkv_kernel<<<MQ / 128, 256, 0, stream>>>(hn, qwb + i * 192 * 64, qkv_b + i * 192,
                                                 qs, ks, vs);
        attn_kernel<<<BQ * HH, 256, 0, stream>>>(qs, ks, vs, h);
        ln_kernel<<<MP / 4, 256, 0, stream>>>(h, ln_g + i * DD, ln_b + i * DD, hn);
        if (!precast)
            cast_bf16<<<2048, 256, 0, stream>>>(w1 + (size_t)i * FF * DD, w1b, (FF * DD) / 4);
        gemm_bt<1, 1><<<1200, 256, 0, stream>>>(hn, w1i, b1 + i * FF, 768, 3072,
                                                nullptr, u, nullptr, 24, 50);
        if (!precast)
            cast_bf16<<<2048, 256, 0, stream>>>(w2 + (size_t)i * FF * DD, w2b, (FF * DD) / 4);
        gemm_bt<2, 4><<<1200, 256, 0, stream>>>(u, w2i, b2 + i * DD, 3072, 768,
                                                h, nullptr, nullptr, 6, 50);
    }
    head_kernel<<<dim3(4, BQ), 256, 0, stream>>>(h, head_w, head_b, (float*)d_out);
}

// Round 3
// 2649.761 us; speedup vs baseline: 1.2613x; 1.2613x over previous
//
#include <hip/hip_runtime.h>
#include <hip/hip_bf16.h>
#include <math.h>

typedef __bf16 bf16;
typedef bf16 bf16x8 __attribute__((ext_vector_type(8)));
typedef bf16 bf16x4 __attribute__((ext_vector_type(4)));
typedef float f32x4 __attribute__((ext_vector_type(4)));

#define BQ 32
#define TT 197
#define DD 768
#define HH 12
#define FF 3072
#define LL 12
#define TP 224
#define MR 6304   // B*T
#define MP 6400   // padded to 50*128
#define MQ 75648  // B*T*H rows for qkv gemm (591*128)
#define KST 72    // K LDS row stride (elements)
#define PST 232   // P / Vt LDS row stride (elements)

typedef __attribute__((address_space(1))) const void gv_t;
typedef __attribute__((address_space(3))) void lv_t;

__device__ __forceinline__ void gld16(const void* g, void* l) {
    __builtin_amdgcn_global_load_lds((gv_t*)g, (lv_t*)l, 16, 0, 0);
}

__device__ __forceinline__ f32x4 mfma16(bf16x8 a, bf16x8 b, f32x4 c) {
    return __builtin_amdgcn_mfma_f32_16x16x32_bf16(a, b, c, 0, 0, 0);
}

// bijective XCD swizzle (m204): consecutive wgid stay on one XCD
__device__ __forceinline__ int xcd_swz(int bid, int nwg) {
    int q = nwg >> 3, r = nwg & 7;
    int xcd = bid & 7, pos = bid >> 3;
    int base = (xcd < r) ? xcd * (q + 1) : r * (q + 1) + (xcd - r) * q;
    return base + pos;
}

// ---------------------------------------------------------------------------
// C = A(M,K) @ W(N,K)^T GEMM, 128x128 tile, BK=64, 4 waves.
// EPI 0: +bias, patch-embed -> h rows (b*197+1+n) += pos_enc (fp32 write)
// EPI 1: +bias, exact GELU -> bf16 out (stride N)
// EPI 2: +bias, direct residual += into fp32 out (stride 768), SPLITK==1 only
// EPI 3: raw partial write -> outF[ks*MP*DD + row*DD + col] (no bias)
// ---------------------------------------------------------------------------
template <int EPI, int SPLITK>
__global__ __launch_bounds__(256, 4)
void gemm_bt(const bf16* __restrict__ A, const bf16* __restrict__ W,
             const float* __restrict__ bias, int K, int N,
             float* __restrict__ outF, bf16* __restrict__ outB,
             const float* __restrict__ pos, int gx, int gy) {
    __shared__ bf16 As[128 * 64];
    __shared__ bf16 Bs[128 * 64];
    const int tid = threadIdx.x;
    const int lane = tid & 63, wave = tid >> 6;
    const int wm = wave >> 1, wn = wave & 1;

    const int wgid = xcd_swz(blockIdx.x, gridDim.x);
    const int ks   = (SPLITK > 1) ? wgid / (gx * gy) : 0;
    const int rem  = (SPLITK > 1) ? wgid % (gx * gy) : wgid;
    const int bx = rem % gx, by = rem / gx;
    const int m0 = by * 128, n0 = bx * 128;

    const int kb = K / SPLITK;
    const int k0 = ks * kb, k1 = k0 + kb;

    f32x4 acc[4][4] = {};
    const bf16* Ab = A + (size_t)m0 * K;
    const bf16* Wb = W + (size_t)n0 * K;

    for (int kt = k0; kt < k1; kt += 64) {
#pragma unroll
        for (int i = 0; i < 4; i++) {
            int idx = i * 256 + tid;
            int row = idx >> 3, cb = idx & 7;
            gld16(Ab + (size_t)row * K + kt + cb * 8, As + idx * 8);
            gld16(Wb + (size_t)row * K + kt + cb * 8, Bs + idx * 8);
        }
        __syncthreads();
        bf16x8 af[4][2], bfr[4][2];
#pragma unroll
        for (int f = 0; f < 4; f++) {
            int ra = (wm * 64 + f * 16 + (lane & 15)) * 64 + ((lane >> 4) * 8);
            af[f][0] = *(const bf16x8*)(As + ra);
            af[f][1] = *(const bf16x8*)(As + ra + 32);
            int rb = (wn * 64 + f * 16 + (lane & 15)) * 64 + ((lane >> 4) * 8);
            bfr[f][0] = *(const bf16x8*)(Bs + rb);
            bfr[f][1] = *(const bf16x8*)(Bs + rb + 32);
        }
#pragma unroll
        for (int kh = 0; kh < 2; kh++)
#pragma unroll
            for (int mf = 0; mf < 4; mf++)
#pragma unroll
                for (int nf = 0; nf < 4; nf++)
                    acc[mf][nf] = mfma16(af[mf][kh], bfr[nf][kh], acc[mf][nf]);
        __syncthreads();
    }

    const int r0 = m0 + wm * 64, c0 = n0 + wn * 64;
#pragma unroll
    for (int mf = 0; mf < 4; mf++) {
#pragma unroll
        for (int j = 0; j < 4; j++) {
            int row = r0 + mf * 16 + ((lane >> 4) * 4) + j;
            int pb = 0, pn = 0;
            if (EPI == 0) { pb = row / 196; pn = row - pb * 196; }
#pragma unroll
            for (int nf = 0; nf < 4; nf++) {
                int col = c0 + nf * 16 + (lane & 15);
                float v = acc[mf][nf][j];
                if (EPI == 0) {
                    v += bias[col];
                    float pv = pos[(size_t)(1 + pn) * DD + col];
                    outF[(size_t)(pb * TT + 1 + pn) * DD + col] = v + pv;
                } else if (EPI == 1) {
                    v += bias[col];
                    float g = 0.5f * v * (1.0f + erff(v * 0.70710678118654752f));
                    outB[(size_t)row * N + col] = (bf16)g;
                } else if (EPI == 2) {
                    v += bias[col];
                    if (row < MR) outF[(size_t)row * DD + col] += v;
                } else {
                    outF[(size_t)(ks * MP + row) * DD + col] = v;
                }
            }
        }
    }
}

// ---------------------------------------------------------------------------
// QKV: A = hn viewed as (B*T*H, 64) contiguous (since D = H*64).
// C (MQ,192) = A @ qkv_w(192,64)^T + qkv_b, scattered to Q/K/V (B*H, 224, 64)
// ---------------------------------------------------------------------------
__global__ __launch_bounds__(256, 2)
void qkv_kernel(const bf16* __restrict__ hn, const bf16* __restrict__ qw,
                const float* __restrict__ qb, bf16* __restrict__ Q,
                bf16* __restrict__ Kb, bf16* __restrict__ Vb) {
    __shared__ bf16 Asm[128 * 64];
    __shared__ bf16 Wsm[192 * 64];
    const int tid = threadIdx.x, lane = tid & 63, wave = tid >> 6;
    const size_t base = (size_t)blockIdx.x * (128 * 64);
#pragma unroll
    for (int i = 0; i < 4; i++) { int idx = i * 256 + tid; gld16(hn + base + idx * 8, Asm + idx * 8); }
#pragma unroll
    for (int i = 0; i < 6; i++) { int idx = i * 256 + tid; gld16(qw + idx * 8, Wsm + idx * 8); }
    __syncthreads();

    bf16x8 af[2][2];
#pragma unroll
    for (int mf = 0; mf < 2; mf++) {
        int ra = (wave * 32 + mf * 16 + (lane & 15)) * 64 + (lane >> 4) * 8;
        af[mf][0] = *(const bf16x8*)(Asm + ra);
        af[mf][1] = *(const bf16x8*)(Asm + ra + 32);
    }
    f32x4 acc[2][12] = {};
#pragma unroll
    for (int nf = 0; nf < 12; nf++) {
        int rb = (nf * 16 + (lane & 15)) * 64 + (lane >> 4) * 8;
        bf16x8 b0 = *(const bf16x8*)(Wsm + rb);
        bf16x8 b1 = *(const bf16x8*)(Wsm + rb + 32);
#pragma unroll
        for (int mf = 0; mf < 2; mf++) {
            acc[mf][nf] = mfma16(af[mf][0], b0, acc[mf][nf]);
            acc[mf][nf] = mfma16(af[mf][1], b1, acc[mf][nf]);
        }
    }
    const int r0 = blockIdx.x * 128 + wave * 32;
#pragma unroll
    for (int mf = 0; mf < 2; mf++)
#pragma unroll
        for (int j = 0; j < 4; j++) {
            int r = r0 + mf * 16 + (lane >> 4) * 4 + j;
            int bt = r / 12, hh = r - bt * 12;
            int b = bt / 197, t = bt - b * 197;
            size_t dbase = ((size_t)(b * HH + hh) * TP + t) * 64;
#pragma unroll
            for (int nf = 0; nf < 12; nf++) {
                int col = nf * 16 + (lane & 15);
                float v = acc[mf][nf][j] + qb[col];
                int sel = nf >> 2, e = col & 63;
                bf16* dst = (sel == 0) ? Q : (sel == 1 ? Kb : Vb);
                dst[dbase + e] = (bf16)v;
            }
        }
}

// ---------------------------------------------------------------------------
// Fused attention per (b,h): scores = QK^T*0.125 (masked >=197), softmax,
// O = P@V, h += O (residual). K in LDS [224][72], V transposed [64][232],
// P per-wave [16][232].
// ---------------------------------------------------------------------------
__global__ __launch_bounds__(256, 1)
void attn_kernel(const bf16* __restrict__ Q, const bf16* __restrict__ Kg,
                 const bf16* __restrict__ Vg, float* __restrict__ h) {
    __shared__ bf16 Ks[TP * KST];
    __shared__ bf16 Vt[64 * PST];
    __shared__ bf16 Pw[4 * 16 * PST];
    const int tid = threadIdx.x, lane = tid & 63, wave = tid >> 6;
    const int bh = blockIdx.x;
    const int b = bh / HH, hh = bh - b * HH;
    const bf16* Kp = Kg + (size_t)bh * TP * 64;
    const bf16* Vp = Vg + (size_t)bh * TP * 64;
    const bf16* Qp = Q + (size_t)bh * TP * 64;

#pragma unroll
    for (int i = 0; i < 7; i++) {
        int idx = i * 256 + tid;
        int row = idx >> 3, cb = idx & 7;
        bf16x8 kv = *(const bf16x8*)(Kp + idx * 8);
        *(bf16x8*)(Ks + row * KST + cb * 8) = kv;
        bf16x8 vv = *(const bf16x8*)(Vp + idx * 8);
#pragma unroll
        for (int j = 0; j < 8; j++) Vt[(cb * 8 + j) * PST + row] = vv[j];
    }
    __syncthreads();

    bf16* Pm = Pw + wave * 16 * PST;
    for (int ch = wave; ch < 13; ch += 4) {
        const int q0 = ch * 16;
        const bf16* qp = Qp + (q0 + (lane & 15)) * 64 + (lane >> 4) * 8;
        bf16x8 aq0 = *(const bf16x8*)qp;
        bf16x8 aq1 = *(const bf16x8*)(qp + 32);
        f32x4 s[14] = {};
#pragma unroll
        for (int nf = 0; nf < 14; nf++) {
            int rb = (nf * 16 + (lane & 15)) * KST + (lane >> 4) * 8;
            bf16x8 b0 = *(const bf16x8*)(Ks + rb);
            bf16x8 b1 = *(const bf16x8*)(Ks + rb + 32);
            s[nf] = mfma16(aq0, b0, s[nf]);
            s[nf] = mfma16(aq1, b1, s[nf]);
        }
        const int colbase = lane & 15;
#pragma unroll
        for (int j = 0; j < 4; j++) {
            float pv[14];
            float m = -1e30f;
#pragma unroll
            for (int nf = 0; nf < 14; nf++) {
                int col = nf * 16 + colbase;
                float v = s[nf][j] * 0.125f;
                v = (col < TT) ? v : -1e30f;
                pv[nf] = v;
                m = fmaxf(m, v);
            }
#pragma unroll
            for (int dd = 1; dd < 16; dd <<= 1) m = fmaxf(m, __shfl_xor(m, dd));
            float sum = 0.0f;
#pragma unroll
            for (int nf = 0; nf < 14; nf++) { float e = __expf(pv[nf] - m); pv[nf] = e; sum += e; }
#pragma unroll
            for (int dd = 1; dd < 16; dd <<= 1) sum += __shfl_xor(sum, dd);
            float inv = 1.0f / sum;
            int pr = (lane >> 4) * 4 + j;
#pragma unroll
            for (int nf = 0; nf < 14; nf++)
                Pm[pr * PST + nf * 16 + colbase] = (bf16)(pv[nf] * inv);
        }
        asm volatile("s_waitcnt lgkmcnt(0)" ::: "memory");
        f32x4 o[4] = {};
#pragma unroll
        for (int ks = 0; ks < 7; ks++) {
            bf16x8 pa = *(const bf16x8*)(Pm + (lane & 15) * PST + ks * 32 + (lane >> 4) * 8);
#pragma unroll
            for (int nf = 0; nf < 4; nf++) {
                bf16x8 bv = *(const bf16x8*)(Vt + (nf * 16 + (lane & 15)) * PST + ks * 32 + (lane >> 4) * 8);
                o[nf] = mfma16(pa, bv, o[nf]);
            }
        }
#pragma unroll
        for (int nf = 0; nf < 4; nf++)
#pragma unroll
            for (int j = 0; j < 4; j++) {
                int qr = q0 + (lane >> 4) * 4 + j;
                if (qr < TT) {
                    int d = nf * 16 + (lane & 15);
                    h[(size_t)(b * TT + qr) * DD + hh * 64 + d] += o[nf][j];
                }
            }
    }
}

// ---------------------------------------------------------------------------
// LayerNorm, one row per wave (4 rows/block), fp32 in -> bf16 out
// ---------------------------------------------------------------------------
__device__ __forceinline__ void ln_core(float4 a[3], const float* g, const float* bt,
                                        bf16* hn, int row, int lane) {
    float sum = 0.0f;
#pragma unroll
    for (int i = 0; i < 3; i++) sum += a[i].x + a[i].y + a[i].z + a[i].w;
#pragma unroll
    for (int dd = 1; dd < 64; dd <<= 1) sum += __shfl_xor(sum, dd);
    const float mu = sum * (1.0f / 768.0f);
    float sq = 0.0f;
#pragma unroll
    for (int i = 0; i < 3; i++) {
        float dx = a[i].x - mu, dy = a[i].y - mu, dz = a[i].z - mu, dw = a[i].w - mu;
        sq += dx * dx + dy * dy + dz * dz + dw * dw;
    }
#pragma unroll
    for (int dd = 1; dd < 64; dd <<= 1) sq += __shfl_xor(sq, dd);
    const float is = rsqrtf(sq * (1.0f / 768.0f) + 1e-5f);
#pragma unroll
    for (int i = 0; i < 3; i++) {
        int c4 = lane + i * 64;
        float4 gg = ((const float4*)g)[c4];
        float4 bb = ((const float4*)bt)[c4];
        bf16x4 o;
        o[0] = (bf16)((a[i].x - mu) * is * gg.x + bb.x);
        o[1] = (bf16)((a[i].y - mu) * is * gg.y + bb.y);
        o[2] = (bf16)((a[i].z - mu) * is * gg.z + bb.z);
        o[3] = (bf16)((a[i].w - mu) * is * gg.w + bb.w);
        ((bf16x4*)(hn + (size_t)row * DD))[c4] = o;
    }
}

__global__ void ln_kernel(const float* __restrict__ h, const float* __restrict__ g,
                          const float* __restrict__ bt, bf16* __restrict__ hn) {
    const int lane = threadIdx.x & 63, wave = threadIdx.x >> 6;
    const int row = blockIdx.x * 4 + wave;
    const float* x = h + (size_t)row * DD;
    float4 a[3];
#pragma unroll
    for (int i = 0; i < 3; i++) a[i] = ((const float4*)x)[lane + i * 64];
    ln_core(a, g, bt, hn, row, lane);
}

// h += sum(4 partials) + b2; write h; hn = LN(h)
__global__ void ln_acc_kernel(float* __restrict__ h, const float* __restrict__ part,
                              const float* __restrict__ b2,
                              const float* __restrict__ g, const float* __restrict__ bt,
                              bf16* __restrict__ hn) {
    const int lane = threadIdx.x & 63, wave = threadIdx.x >> 6;
    const int row = blockIdx.x * 4 + wave;
    float* x = h + (size_t)row * DD;
    float4 a[3];
#pragma unroll
    for (int i = 0; i < 3; i++) a[i] = ((const float4*)x)[lane + i * 64];
#pragma unroll
    for (int s = 0; s < 4; s++) {
        const float4* ps = (const float4*)(part + ((size_t)s * MP + row) * DD);
#pragma unroll
        for (int i = 0; i < 3; i++) {
            float4 p = ps[lane + i * 64];
            a[i].x += p.x; a[i].y += p.y; a[i].z += p.z; a[i].w += p.w;
        }
    }
#pragma unroll
    for (int i = 0; i < 3; i++) {
        float4 bb = ((const float4*)b2)[lane + i * 64];
        a[i].x += bb.x; a[i].y += bb.y; a[i].z += bb.z; a[i].w += bb.w;
        ((float4*)x)[lane + i * 64] = a[i];
    }
    ln_core(a, g, bt, hn, row, lane);
}

// ---------------------------------------------------------------------------
__global__ void patch_extract(const float* __restrict__ x, bf16* __restrict__ p) {
    int idx = blockIdx.x * 256 + threadIdx.x;
    if (idx >= 6272 * 768) return;
    int k = idx % 768, row = idx / 768;
    int c = k % 3, pc = (k / 3) % 16, pr = k / 48;
    int b = row / 196, n = row - b * 196;
    int hp = n / 14, wp = n - hp * 14;
    p[idx] = (bf16)x[((size_t)(b * 3 + c) * 224 + hp * 16 + pr) * 224 + wp * 16 + pc];
}

__global__ void cast_bf16(const float* __restrict__ in, bf16* __restrict__ out, int n4) {
    int i = blockIdx.x * 256 + threadIdx.x;
    int stride = gridDim.x * 256;
    for (; i < n4; i += stride) {
        float4 v = ((const float4*)in)[i];
        bf16x4 o;
        o[0] = (bf16)v.x; o[1] = (bf16)v.y; o[2] = (bf16)v.z; o[3] = (bf16)v.w;
        ((bf16x4*)out)[i] = o;
    }
}

__global__ void cls_init(const float* __restrict__ cls, const float* __restrict__ pos,
                         float* __restrict__ h) {
    int i = blockIdx.x * 256 + threadIdx.x;
    if (i >= BQ * DD) return;
    int b = i / DD, c = i - b * DD;
    h[(size_t)(b * TT) * DD + c] = cls[c] + pos[c];
}

__global__ void head_kernel(const float* __restrict__ h, const float* __restrict__ hw,
                            const float* __restrict__ hb, float* __restrict__ out) {
    __shared__ float xr[DD];
    const int b = blockIdx.y;
    const int n = blockIdx.x * 256 + threadIdx.x;
    for (int i = threadIdx.x; i < DD; i += 256) xr[i] = h[(size_t)(b * TT) * DD + i];
    __syncthreads();
    if (n < 1000) {
        float s = hb[n];
        const float4* w = (const float4*)(hw + (size_t)n * DD);
        float acc = 0.0f;
#pragma unroll 4
        for (int k = 0; k < DD / 4; k++) {
            float4 wv = w[k];
            float4 xv = ((const float4*)xr)[k];
            acc += wv.x * xv.x + wv.y * xv.y + wv.z * xv.z + wv.w * xv.w;
        }
        out[b * 1000 + n] = s + acc;
    }
}

// ---------------------------------------------------------------------------
extern "C" void kernel_launch(void* const* d_in, const int* in_sizes, int n_in,
                              void* d_out, int out_size, void* d_ws, size_t ws_size,
                              hipStream_t stream) {
    const float* x       = (const float*)d_in[0];
    const float* patch_w = (const float*)d_in[1];
    const float* patch_b = (const float*)d_in[2];
    const float* pos_enc = (const float*)d_in[3];
    const float* cls_tok = (const float*)d_in[4];
    const float* qkv_w   = (const float*)d_in[5];
    const float* qkv_b   = (const float*)d_in[6];
    const float* ln_g    = (const float*)d_in[7];
    const float* ln_b    = (const float*)d_in[8];
    const float* w1      = (const float*)d_in[9];
    const float* b1      = (const float*)d_in[10];
    const float* w2      = (const float*)d_in[11];
    const float* b2      = (const float*)d_in[12];
    const float* head_w  = (const float*)d_in[13];
    const float* head_b  = (const float*)d_in[14];

    char* wp = (char*)d_ws;
    auto carve = [&](size_t bytes) {
        char* r = wp;
        wp += (bytes + 255) & ~(size_t)255;
        return r;
    };
    auto fits = [&](size_t bytes) {
        return (size_t)(wp - (char*)d_ws) + bytes + 256 <= ws_size;
    };
    float* h  = (float*)carve((size_t)MP * DD * 4);
    bf16* hn  = (bf16*)carve((size_t)MP * DD * 2);
    bf16* u   = (bf16*)carve((size_t)MP * FF * 2);
    bf16* qs  = (bf16*)carve((size_t)BQ * HH * TP * 64 * 2);
    bf16* ks  = (bf16*)carve((size_t)BQ * HH * TP * 64 * 2);
    bf16* vs  = (bf16*)carve((size_t)BQ * HH * TP * 64 * 2);
    bf16* p   = (bf16*)carve((size_t)6272 * DD * 2);
    bf16* pwb = (bf16*)carve((size_t)DD * DD * 2);
    bf16* qwb = (bf16*)carve((size_t)LL * 192 * 64 * 2);

    // split-K partials (4 x MP x DD fp32), if ws allows
    float* part = nullptr;
    if (fits((size_t)4 * MP * DD * 4)) part = (float*)carve((size_t)4 * MP * DD * 4);
    const bool use_part = (part != nullptr);

    // precast-all weights, if ws allows
    const size_t wfull = (size_t)LL * FF * DD * 2;
    const bool precast = fits(2 * (wfull + 256));
    bf16* w1b = (bf16*)carve(precast ? wfull : (size_t)FF * DD * 2);
    bf16* w2b = (bf16*)carve(precast ? wfull : (size_t)DD * FF * 2);

    cast_bf16<<<512, 256, 0, stream>>>(patch_w, pwb, (DD * DD) / 4);
    cast_bf16<<<144, 256, 0, stream>>>(qkv_w, qwb, (LL * 192 * 64) / 4);
    if (precast) {
        cast_bf16<<<4096, 256, 0, stream>>>(w1, w1b, (LL * FF * DD) / 4);
        cast_bf16<<<4096, 256, 0, stream>>>(w2, w2b, (LL * FF * DD) / 4);
    }
    patch_extract<<<18816, 256, 0, stream>>>(x, p);
    cls_init<<<96, 256, 0, stream>>>(cls_tok, pos_enc, h);
    gemm_bt<0, 1><<<294, 256, 0, stream>>>(p, pwb, patch_b, 768, 768, h, nullptr,
                                           pos_enc, 6, 49);

    for (int i = 0; i < LL; i++) {
        const bf16* w1i = precast ? (w1b + (size_t)i * FF * DD) : w1b;
        const bf16* w2i = precast ? (w2b + (size_t)i * FF * DD) : w2b;

        // ln1 (fused with previous layer's MLP2 partial reduction + b2 + residual)
        if (use_part && i > 0)
            ln_acc_kernel<<<MP / 4, 256, 0, stream>>>(h, part, b2 + (i - 1) * DD,
                                                      ln_g + i * DD, ln_b + i * DD, hn);
        else
            ln_kernel<<<MP / 4, 256, 0, stream>>>(h, ln_g + i * DD, ln_b + i * DD, hn);

        qkv_kernel<<<MQ / 128, 256, 0, stream>>>(hn, qwb + i * 192 * 64, qkv_b + i * 192,
                                                 qs, ks, vs);
        attn_kernel<<<BQ * HH, 256, 0, stream>>>(qs, ks, vs, h);
        ln_kernel<<<MP / 4, 256, 0, stream>>>(h, ln_g + i * DD, ln_b + i * DD, hn);
        if (!precast)
            cast_bf16<<<2048, 256, 0, stream>>>(w1 + (size_t)i * FF * DD, w1b, (FF * DD) / 4);
        gemm_bt<1, 1><<<1200, 256, 0, stream>>>(hn, w1i, b1 + i * FF, 768, 3072,
                                                nullptr, u, nullptr, 24, 50);
        if (!precast)
            cast_bf16<<<2048, 256, 0, stream>>>(w2 + (size_t)i * FF * DD, w2b, (FF * DD) / 4);
        if (use_part)
            gemm_bt<3, 4><<<1200, 256, 0, stream>>>(u, w2i, nullptr, 3072, 768,
                                                    part, nullptr, nullptr, 6, 50);
        else
            gemm_bt<2, 1><<<300, 256, 0, stream>>>(u, w2i, b2 + i * DD, 3072, 768,
                                                   h, nullptr, nullptr, 6, 50);
    }
    if (use_part)  // final reduction of layer 11's MLP2 into h (hn output unused)
        ln_acc_kernel<<<MP / 4, 256, 0, stream>>>(h, part, b2 + 11 * DD,
                                                  ln_g, ln_b, hn);
    head_kernel<<<dim3(4, BQ), 256, 0, stream>>>(h, head_w, head_b, (float*)d_out);
}

// Round 4
// 2588.683 us; speedup vs baseline: 1.2911x; 1.0236x over previous
//
#include <hip/hip_runtime.h>
#include <hip/hip_bf16.h>
#include <math.h>

typedef __bf16 bf16;
typedef bf16 bf16x8 __attribute__((ext_vector_type(8)));
typedef bf16 bf16x4 __attribute__((ext_vector_type(4)));
typedef float f32x4 __attribute__((ext_vector_type(4)));

#define BQ 32
#define TT 197
#define DD 768
#define HH 12
#define FF 3072
#define LL 12
#define TP 224
#define MR 6304   // B*T
#define MP 6400   // padded to 50*128
#define MQ 75648  // B*T*H rows for qkv gemm (591*128)
#define KST 72    // K LDS row stride (elements)
#define PST 232   // P / Vt LDS row stride (elements)
#define NSPLIT 2  // MLP2 split-K factor

typedef __attribute__((address_space(1))) const void gv_t;
typedef __attribute__((address_space(3))) void lv_t;

__device__ __forceinline__ void gld16(const void* g, void* l) {
    __builtin_amdgcn_global_load_lds((gv_t*)g, (lv_t*)l, 16, 0, 0);
}

__device__ __forceinline__ f32x4 mfma16(bf16x8 a, bf16x8 b, f32x4 c) {
    return __builtin_amdgcn_mfma_f32_16x16x32_bf16(a, b, c, 0, 0, 0);
}

// bijective XCD swizzle (m204): consecutive wgid stay on one XCD
__device__ __forceinline__ int xcd_swz(int bid, int nwg) {
    int q = nwg >> 3, r = nwg & 7;
    int xcd = bid & 7, pos = bid >> 3;
    int base = (xcd < r) ? xcd * (q + 1) : r * (q + 1) + (xcd - r) * q;
    return base + pos;
}

// ---------------------------------------------------------------------------
// C = A(M,K) @ W(N,K)^T GEMM, 128x128 tile, BK=64, 4 waves.
// LDS double-buffered (stage(t+1) issued before compute(t), one barrier per
// K-step -> vmcnt drain lands after MFMAs). Column-block XOR swizzle
// (cb ^ row&7) applied on the global SOURCE side of global_load_lds (LDS dest
// linear, rule #21) and mirrored on the ds_read side -> bank-balanced reads.
// EPI 0: +bias, patch-embed -> h rows (b*197+1+n) += pos_enc (fp32 write)
// EPI 1: +bias, exact GELU -> bf16 out (stride N)
// EPI 2: +bias, direct residual += into fp32 out (stride 768)
// EPI 3: raw partial write -> outF[ks*MP*DD + row*DD + col] (no bias)
// ---------------------------------------------------------------------------
template <int EPI, int SPLITK>
__global__ __launch_bounds__(256, 2)
void gemm_bt(const bf16* __restrict__ A, const bf16* __restrict__ W,
             const float* __restrict__ bias, int K, int N,
             float* __restrict__ outF, bf16* __restrict__ outB,
             const float* __restrict__ pos, int gx, int gy) {
    __shared__ bf16 As[2][128 * 64];
    __shared__ bf16 Bs[2][128 * 64];
    const int tid = threadIdx.x;
    const int lane = tid & 63, wave = tid >> 6;
    const int wm = wave >> 1, wn = wave & 1;

    const int wgid = xcd_swz(blockIdx.x, gridDim.x);
    const int ks   = (SPLITK > 1) ? wgid / (gx * gy) : 0;
    const int rem  = (SPLITK > 1) ? wgid % (gx * gy) : wgid;
    const int bx = rem % gx, by = rem / gx;
    const int m0 = by * 128, n0 = bx * 128;

    const int kb = K / SPLITK;
    const int k0 = ks * kb;
    const int nt = kb / 64;

    f32x4 acc[4][4] = {};
    const bf16* Ab = A + (size_t)m0 * K;
    const bf16* Wb = W + (size_t)n0 * K;

    auto stage = [&](int buf, int kt) {
#pragma unroll
        for (int i = 0; i < 4; i++) {
            int idx = i * 256 + tid;
            int row = idx >> 3, cb = idx & 7;
            int gcb = cb ^ (row & 7);   // pre-swizzled source column-block
            gld16(Ab + (size_t)row * K + kt + gcb * 8, &As[buf][idx * 8]);
            gld16(Wb + (size_t)row * K + kt + gcb * 8, &Bs[buf][idx * 8]);
        }
    };

    stage(0, k0);
    __syncthreads();          // compiler drains vmcnt(0) here: buf0 ready
    int cur = 0;
    for (int t = 0; t < nt; ++t) {
        if (t + 1 < nt) stage(cur ^ 1, k0 + (t + 1) * 64);
        bf16x8 af[4][2], bfr[4][2];
#pragma unroll
        for (int f = 0; f < 4; f++) {
            int rowa = wm * 64 + f * 16 + (lane & 15);
            int ma = rowa & 7, ca = lane >> 4;
            af[f][0] = *(const bf16x8*)(&As[cur][rowa * 64 + ((ca    ) ^ ma) * 8]);
            af[f][1] = *(const bf16x8*)(&As[cur][rowa * 64 + ((ca + 4) ^ ma) * 8]);
            int rowb = wn * 64 + f * 16 + (lane & 15);
            int mb = rowb & 7;
            bfr[f][0] = *(const bf16x8*)(&Bs[cur][rowb * 64 + ((ca    ) ^ mb) * 8]);
            bfr[f][1] = *(const bf16x8*)(&Bs[cur][rowb * 64 + ((ca + 4) ^ mb) * 8]);
        }
#pragma unroll
        for (int kh = 0; kh < 2; kh++)
#pragma unroll
            for (int mf = 0; mf < 4; mf++)
#pragma unroll
                for (int nf = 0; nf < 4; nf++)
                    acc[mf][nf] = mfma16(af[mf][kh], bfr[nf][kh], acc[mf][nf]);
        __syncthreads();      // drains stage(t+1); protects buf[cur] reuse
        cur ^= 1;
    }

    const int r0 = m0 + wm * 64, c0 = n0 + wn * 64;
#pragma unroll
    for (int mf = 0; mf < 4; mf++) {
#pragma unroll
        for (int j = 0; j < 4; j++) {
            int row = r0 + mf * 16 + ((lane >> 4) * 4) + j;
            int pb = 0, pn = 0;
            if (EPI == 0) { pb = row / 196; pn = row - pb * 196; }
#pragma unroll
            for (int nf = 0; nf < 4; nf++) {
                int col = c0 + nf * 16 + (lane & 15);
                float v = acc[mf][nf][j];
                if (EPI == 0) {
                    v += bias[col];
                    float pv = pos[(size_t)(1 + pn) * DD + col];
                    outF[(size_t)(pb * TT + 1 + pn) * DD + col] = v + pv;
                } else if (EPI == 1) {
                    v += bias[col];
                    float g = 0.5f * v * (1.0f + erff(v * 0.70710678118654752f));
                    outB[(size_t)row * N + col] = (bf16)g;
                } else if (EPI == 2) {
                    v += bias[col];
                    if (row < MR) outF[(size_t)row * DD + col] += v;
                } else {
                    outF[(size_t)(ks * MP + row) * DD + col] = v;
                }
            }
        }
    }
}

// ---------------------------------------------------------------------------
// QKV: A = hn viewed as (B*T*H, 64) contiguous (since D = H*64).
// C (MQ,192) = A @ qkv_w(192,64)^T + qkv_b, scattered to Q/K/V (B*H, 224, 64)
// Same source-side XOR swizzle as gemm_bt.
// ---------------------------------------------------------------------------
__global__ __launch_bounds__(256, 2)
void qkv_kernel(const bf16* __restrict__ hn, const bf16* __restrict__ qw,
                const float* __restrict__ qb, bf16* __restrict__ Q,
                bf16* __restrict__ Kb, bf16* __restrict__ Vb) {
    __shared__ bf16 Asm[128 * 64];
    __shared__ bf16 Wsm[192 * 64];
    const int tid = threadIdx.x, lane = tid & 63, wave = tid >> 6;
    const bf16* Ab = hn + (size_t)blockIdx.x * (128 * 64);
#pragma unroll
    for (int i = 0; i < 4; i++) {
        int idx = i * 256 + tid;
        int row = idx >> 3, cb = idx & 7;
        int gcb = cb ^ (row & 7);
        gld16(Ab + (size_t)row * 64 + gcb * 8, Asm + idx * 8);
    }
#pragma unroll
    for (int i = 0; i < 6; i++) {
        int idx = i * 256 + tid;
        int row = idx >> 3, cb = idx & 7;
        int gcb = cb ^ (row & 7);
        gld16(qw + (size_t)row * 64 + gcb * 8, Wsm + idx * 8);
    }
    __syncthreads();

    const int ca = lane >> 4;
    bf16x8 af[2][2];
#pragma unroll
    for (int mf = 0; mf < 2; mf++) {
        int row = wave * 32 + mf * 16 + (lane & 15);
        int m7 = row & 7;
        af[mf][0] = *(const bf16x8*)(Asm + row * 64 + ((ca    ) ^ m7) * 8);
        af[mf][1] = *(const bf16x8*)(Asm + row * 64 + ((ca + 4) ^ m7) * 8);
    }
    f32x4 acc[2][12] = {};
#pragma unroll
    for (int nf = 0; nf < 12; nf++) {
        int row = nf * 16 + (lane & 15);
        int m7 = row & 7;
        bf16x8 b0 = *(const bf16x8*)(Wsm + row * 64 + ((ca    ) ^ m7) * 8);
        bf16x8 b1 = *(const bf16x8*)(Wsm + row * 64 + ((ca + 4) ^ m7) * 8);
#pragma unroll
        for (int mf = 0; mf < 2; mf++) {
            acc[mf][nf] = mfma16(af[mf][0], b0, acc[mf][nf]);
            acc[mf][nf] = mfma16(af[mf][1], b1, acc[mf][nf]);
        }
    }
    const int r0 = blockIdx.x * 128 + wave * 32;
#pragma unroll
    for (int mf = 0; mf < 2; mf++)
#pragma unroll
        for (int j = 0; j < 4; j++) {
            int r = r0 + mf * 16 + (lane >> 4) * 4 + j;
            int bt = r / 12, hh = r - bt * 12;
            int b = bt / 197, t = bt - b * 197;
            size_t dbase = ((size_t)(b * HH + hh) * TP + t) * 64;
#pragma unroll
            for (int nf = 0; nf < 12; nf++) {
                int col = nf * 16 + (lane & 15);
                float v = acc[mf][nf][j] + qb[col];
                int sel = nf >> 2, e = col & 63;
                bf16* dst = (sel == 0) ? Q : (sel == 1 ? Kb : Vb);
                dst[dbase + e] = (bf16)v;
            }
        }
}

// ---------------------------------------------------------------------------
// Fused attention per (b,h): scores = QK^T*0.125 (masked >=197), softmax,
// O = P@V, h += O (residual). K in LDS [224][72], V transposed [64][232],
// P per-wave [16][232].
// ---------------------------------------------------------------------------
__global__ __launch_bounds__(256, 1)
void attn_kernel(const bf16* __restrict__ Q, const bf16* __restrict__ Kg,
                 const bf16* __restrict__ Vg, float* __restrict__ h) {
    __shared__ bf16 Ks[TP * KST];
    __shared__ bf16 Vt[64 * PST];
    __shared__ bf16 Pw[4 * 16 * PST];
    const int tid = threadIdx.x, lane = tid & 63, wave = tid >> 6;
    const int bh = blockIdx.x;
    const int b = bh / HH, hh = bh - b * HH;
    const bf16* Kp = Kg + (size_t)bh * TP * 64;
    const bf16* Vp = Vg + (size_t)bh * TP * 64;
    const bf16* Qp = Q + (size_t)bh * TP * 64;

#pragma unroll
    for (int i = 0; i < 7; i++) {
        int idx = i * 256 + tid;
        int row = idx >> 3, cb = idx & 7;
        bf16x8 kv = *(const bf16x8*)(Kp + idx * 8);
        *(bf16x8*)(Ks + row * KST + cb * 8) = kv;
        bf16x8 vv = *(const bf16x8*)(Vp + idx * 8);
#pragma unroll
        for (int j = 0; j < 8; j++) Vt[(cb * 8 + j) * PST + row] = vv[j];
    }
    __syncthreads();

    bf16* Pm = Pw + wave * 16 * PST;
    for (int ch = wave; ch < 13; ch += 4) {
        const int q0 = ch * 16;
        const bf16* qp = Qp + (q0 + (lane & 15)) * 64 + (lane >> 4) * 8;
        bf16x8 aq0 = *(const bf16x8*)qp;
        bf16x8 aq1 = *(const bf16x8*)(qp + 32);
        f32x4 s[14] = {};
#pragma unroll
        for (int nf = 0; nf < 14; nf++) {
            int rb = (nf * 16 + (lane & 15)) * KST + (lane >> 4) * 8;
            bf16x8 b0 = *(const bf16x8*)(Ks + rb);
            bf16x8 b1 = *(const bf16x8*)(Ks + rb + 32);
            s[nf] = mfma16(aq0, b0, s[nf]);
            s[nf] = mfma16(aq1, b1, s[nf]);
        }
        const int colbase = lane & 15;
#pragma unroll
        for (int j = 0; j < 4; j++) {
            float pv[14];
            float m = -1e30f;
#pragma unroll
            for (int nf = 0; nf < 14; nf++) {
                int col = nf * 16 + colbase;
                float v = s[nf][j] * 0.125f;
                v = (col < TT) ? v : -1e30f;
                pv[nf] = v;
                m = fmaxf(m, v);
            }
#pragma unroll
            for (int dd = 1; dd < 16; dd <<= 1) m = fmaxf(m, __shfl_xor(m, dd));
            float sum = 0.0f;
#pragma unroll
            for (int nf = 0; nf < 14; nf++) { float e = __expf(pv[nf] - m); pv[nf] = e; sum += e; }
#pragma unroll
            for (int dd = 1; dd < 16; dd <<= 1) sum += __shfl_xor(sum, dd);
            float inv = 1.0f / sum;
            int pr = (lane >> 4) * 4 + j;
#pragma unroll
            for (int nf = 0; nf < 14; nf++)
                Pm[pr * PST + nf * 16 + colbase] = (bf16)(pv[nf] * inv);
        }
        asm volatile("s_waitcnt lgkmcnt(0)" ::: "memory");
        f32x4 o[4] = {};
#pragma unroll
        for (int ks = 0; ks < 7; ks++) {
            bf16x8 pa = *(const bf16x8*)(Pm + (lane & 15) * PST + ks * 32 + (lane >> 4) * 8);
#pragma unroll
            for (int nf = 0; nf < 4; nf++) {
                bf16x8 bv = *(const bf16x8*)(Vt + (nf * 16 + (lane & 15)) * PST + ks * 32 + (lane >> 4) * 8);
                o[nf] = mfma16(pa, bv, o[nf]);
            }
        }
#pragma unroll
        for (int nf = 0; nf < 4; nf++)
#pragma unroll
            for (int j = 0; j < 4; j++) {
                int qr = q0 + (lane >> 4) * 4 + j;
                if (qr < TT) {
                    int d = nf * 16 + (lane & 15);
                    h[(size_t)(b * TT + qr) * DD + hh * 64 + d] += o[nf][j];
                }
            }
    }
}

// ---------------------------------------------------------------------------
// LayerNorm, one row per wave (4 rows/block), fp32 in -> bf16 out
// ---------------------------------------------------------------------------
__device__ __forceinline__ void ln_core(float4 a[3], const float* g, const float* bt,
                                        bf16* hn, int row, int lane) {
    float sum = 0.0f;
#pragma unroll
    for (int i = 0; i < 3; i++) sum += a[i].x + a[i].y + a[i].z + a[i].w;
#pragma unroll
    for (int dd = 1; dd < 64; dd <<= 1) sum += __shfl_xor(sum, dd);
    const float mu = sum * (1.0f / 768.0f);
    float sq = 0.0f;
#pragma unroll
    for (int i = 0; i < 3; i++) {
        float dx = a[i].x - mu, dy = a[i].y - mu, dz = a[i].z - mu, dw = a[i].w - mu;
        sq += dx * dx + dy * dy + dz * dz + dw * dw;
    }
#pragma unroll
    for (int dd = 1; dd < 64; dd <<= 1) sq += __shfl_xor(sq, dd);
    const float is = rsqrtf(sq * (1.0f / 768.0f) + 1e-5f);
#pragma unroll
    for (int i = 0; i < 3; i++) {
        int c4 = lane + i * 64;
        float4 gg = ((const float4*)g)[c4];
        float4 bb = ((const float4*)bt)[c4];
        bf16x4 o;
        o[0] = (bf16)((a[i].x - mu) * is * gg.x + bb.x);
        o[1] = (bf16)((a[i].y - mu) * is * gg.y + bb.y);
        o[2] = (bf16)((a[i].z - mu) * is * gg.z + bb.z);
        o[3] = (bf16)((a[i].w - mu) * is * gg.w + bb.w);
        ((bf16x4*)(hn + (size_t)row * DD))[c4] = o;
    }
}

__global__ void ln_kernel(const float* __restrict__ h, const float* __restrict__ g,
                          const float* __restrict__ bt, bf16* __restrict__ hn) {
    const int lane = threadIdx.x & 63, wave = threadIdx.x >> 6;
    const int row = blockIdx.x * 4 + wave;
    const float* x = h + (size_t)row * DD;
    float4 a[3];
#pragma unroll
    for (int i = 0; i < 3; i++) a[i] = ((const float4*)x)[lane + i * 64];
    ln_core(a, g, bt, hn, row, lane);
}

// h += sum(NS partials) + b2; write h; hn = LN(h)
template <int NS>
__global__ void ln_acc_kernel(float* __restrict__ h, const float* __restrict__ part,
                              const float* __restrict__ b2,
                              const float* __restrict__ g, const float* __restrict__ bt,
                              bf16* __restrict__ hn) {
    const int lane = threadIdx.x & 63, wave = threadIdx.x >> 6;
    const int row = blockIdx.x * 4 + wave;
    float* x = h + (size_t)row * DD;
    float4 a[3];
#pragma unroll
    for (int i = 0; i < 3; i++) a[i] = ((const float4*)x)[lane + i * 64];
#pragma unroll
    for (int s = 0; s < NS; s++) {
        const float4* ps = (const float4*)(part + ((size_t)s * MP + row) * DD);
#pragma unroll
        for (int i = 0; i < 3; i++) {
            float4 p = ps[lane + i * 64];
            a[i].x += p.x; a[i].y += p.y; a[i].z += p.z; a[i].w += p.w;
        }
    }
#pragma unroll
    for (int i = 0; i < 3; i++) {
        float4 bb = ((const float4*)b2)[lane + i * 64];
        a[i].x += bb.x; a[i].y += bb.y; a[i].z += bb.z; a[i].w += bb.w;
        ((float4*)x)[lane + i * 64] = a[i];
    }
    ln_core(a, g, bt, hn, row, lane);
}

// ---------------------------------------------------------------------------
__global__ void patch_extract(const float* __restrict__ x, bf16* __restrict__ p) {
    int idx = blockIdx.x * 256 + threadIdx.x;
    if (idx >= 6272 * 768) return;
    int k = idx % 768, row = idx / 768;
    int c = k % 3, pc = (k / 3) % 16, pr = k / 48;
    int b = row / 196, n = row - b * 196;
    int hp = n / 14, wp = n - hp * 14;
    p[idx] = (bf16)x[((size_t)(b * 3 + c) * 224 + hp * 16 + pr) * 224 + wp * 16 + pc];
}

__global__ void cast_bf16(const float* __restrict__ in, bf16* __restrict__ out, int n4) {
    int i = blockIdx.x * 256 + threadIdx.x;
    int stride = gridDim.x * 256;
    for (; i < n4; i += stride) {
        float4 v = ((const float4*)in)[i];
        bf16x4 o;
        o[0] = (bf16)v.x; o[1] = (bf16)v.y; o[2] = (bf16)v.z; o[3] = (bf16)v.w;
        ((bf16x4*)out)[i] = o;
    }
}

__global__ void cls_init(const float* __restrict__ cls, const float* __restrict__ pos,
                         float* __restrict__ h) {
    int i = blockIdx.x * 256 + threadIdx.x;
    if (i >= BQ * DD) return;
    int b = i / DD, c = i - b * DD;
    h[(size_t)(b * TT) * DD + c] = cls[c] + pos[c];
}

__global__ void head_kernel(const float* __restrict__ h, const float* __restrict__ hw,
                            const float* __restrict__ hb, float* __restrict__ out) {
    __shared__ float xr[DD];
    const int b = blockIdx.y;
    const int n = blockIdx.x * 256 + threadIdx.x;
    for (int i = threadIdx.x; i < DD; i += 256) xr[i] = h[(size_t)(b * TT) * DD + i];
    __syncthreads();
    if (n < 1000) {
        float s = hb[n];
        const float4* w = (const float4*)(hw + (size_t)n * DD);
        float acc = 0.0f;
#pragma unroll 4
        for (int k = 0; k < DD / 4; k++) {
            float4 wv = w[k];
            float4 xv = ((const float4*)xr)[k];
            acc += wv.x * xv.x + wv.y * xv.y + wv.z * xv.z + wv.w * xv.w;
        }
        out[b * 1000 + n] = s + acc;
    }
}

// ---------------------------------------------------------------------------
extern "C" void kernel_launch(void* const* d_in, const int* in_sizes, int n_in,
                              void* d_out, int out_size, void* d_ws, size_t ws_size,
                              hipStream_t stream) {
    const float* x       = (const float*)d_in[0];
    const float* patch_w = (const float*)d_in[1];
    const float* patch_b = (const float*)d_in[2];
    const float* pos_enc = (const float*)d_in[3];
    const float* cls_tok = (const float*)d_in[4];
    const float* qkv_w   = (const float*)d_in[5];
    const float* qkv_b   = (const float*)d_in[6];
    const float* ln_g    = (const float*)d_in[7];
    const float* ln_b    = (const float*)d_in[8];
    const float* w1      = (const float*)d_in[9];
    const float* b1      = (const float*)d_in[10];
    const float* w2      = (const float*)d_in[11];
    const float* b2      = (const float*)d_in[12];
    const float* head_w  = (const float*)d_in[13];
    const float* head_b  = (const float*)d_in[14];

    char* wp = (char*)d_ws;
    auto carve = [&](size_t bytes) {
        char* r = wp;
        wp += (bytes + 255) & ~(size_t)255;
        return r;
    };
    auto fits = [&](size_t bytes) {
        return (size_t)(wp - (char*)d_ws) + bytes + 256 <= ws_size;
    };
    float* h  = (float*)carve((size_t)MP * DD * 4);
    bf16* hn  = (bf16*)carve((size_t)MP * DD * 2);
    bf16* u   = (bf16*)carve((size_t)MP * FF * 2);
    bf16* qs  = (bf16*)carve((size_t)BQ * HH * TP * 64 * 2);
    bf16* ks  = (bf16*)carve((size_t)BQ * HH * TP * 64 * 2);
    bf16* vs  = (bf16*)carve((size_t)BQ * HH * TP * 64 * 2);
    bf16* p   = (bf16*)carve((size_t)6272 * DD * 2);
    bf16* pwb = (bf16*)carve((size_t)DD * DD * 2);
    bf16* qwb = (bf16*)carve((size_t)LL * 192 * 64 * 2);

    // split-K partials (NSPLIT x MP x DD fp32), if ws allows
    float* part = nullptr;
    if (fits((size_t)NSPLIT * MP * DD * 4))
        part = (float*)carve((size_t)NSPLIT * MP * DD * 4);
    const bool use_part = (part != nullptr);

    // precast-all weights, if ws allows
    const size_t wfull = (size_t)LL * FF * DD * 2;
    const bool precast = fits(2 * (wfull + 256));
    bf16* w1b = (bf16*)carve(precast ? wfull : (size_t)FF * DD * 2);
    bf16* w2b = (bf16*)carve(precast ? wfull : (size_t)DD * FF * 2);

    cast_bf16<<<512, 256, 0, stream>>>(patch_w, pwb, (DD * DD) / 4);
    cast_bf16<<<144, 256, 0, stream>>>(qkv_w, qwb, (LL * 192 * 64) / 4);
    if (precast) {
        cast_bf16<<<4096, 256, 0, stream>>>(w1, w1b, (LL * FF * DD) / 4);
        cast_bf16<<<4096, 256, 0, stream>>>(w2, w2b, (LL * FF * DD) / 4);
    }
    patch_extract<<<18816, 256, 0, stream>>>(x, p);
    cls_init<<<96, 256, 0, stream>>>(cls_tok, pos_enc, h);
    gemm_bt<0, 1><<<294, 256, 0, stream>>>(p, pwb, patch_b, 768, 768, h, nullptr,
                                           pos_enc, 6, 49);

    for (int i = 0; i < LL; i++) {
        const bf16* w1i = precast ? (w1b + (size_t)i * FF * DD) : w1b;
        const bf16* w2i = precast ? (w2b + (size_t)i * FF * DD) : w2b;

        // ln1 (fused with previous layer's MLP2 partial reduction + b2 + residual)
        if (use_part && i > 0)
            ln_acc_kernel<NSPLIT><<<MP / 4, 256, 0, stream>>>(h, part, b2 + (i - 1) * DD,
                                                              ln_g + i * DD, ln_b + i * DD, hn);
        else
            ln_kernel<<<MP / 4, 256, 0, stream>>>(h, ln_g + i * DD, ln_b + i * DD, hn);

        qkv_kernel<<<MQ / 128, 256, 0, stream>>>(hn, qwb + i * 192 * 64, qkv_b + i * 192,
                                                 qs, ks, vs);
        attn_kernel<<<BQ * HH, 256, 0, stream>>>(qs, ks, vs, h);
        ln_kernel<<<MP / 4, 256, 0, stream>>>(h, ln_g + i * DD, ln_b + i * DD, hn);
        if (!precast)
            cast_bf16<<<2048, 256, 0, stream>>>(w1 + (size_t)i * FF * DD, w1b, (FF * DD) / 4);
        gemm_bt<1, 1><<<1200, 256, 0, stream>>>(hn, w1i, b1 + i * FF, 768, 3072,
                                                nullptr, u, nullptr, 24, 50);
        if (!precast)
            cast_bf16<<<2048, 256, 0, stream>>>(w2 + (size_t)i * FF * DD, w2b, (FF * DD) / 4);
        if (use_part)
            gemm_bt<3, NSPLIT><<<300 * NSPLIT, 256, 0, stream>>>(u, w2i, nullptr, 3072, 768,
                                                                 part, nullptr, nullptr, 6, 50);
        else
            gemm_bt<2, 1><<<300, 256, 0, stream>>>(u, w2i, b2 + i * DD, 3072, 768,
                                                   h, nullptr, nullptr, 6, 50);
    }
    if (use_part)  // final reduction of layer 11's MLP2 into h (hn output unused)
        ln_acc_kernel<NSPLIT><<<MP / 4, 256, 0, stream>>>(h, part, b2 + 11 * DD,
                                                          ln_g, ln_b, hn);
    head_kernel<<<dim3(4, BQ), 256, 0, stream>>>(h, head_w, head_b, (float*)d_out);
}

// Round 5
// 2344.925 us; speedup vs baseline: 1.4253x; 1.1040x over previous
//
#include <hip/hip_runtime.h>
#include <hip/hip_bf16.h>
#include <math.h>

typedef __bf16 bf16;
typedef bf16 bf16x8 __attribute__((ext_vector_type(8)));
typedef bf16 bf16x4 __attribute__((ext_vector_type(4)));
typedef float f32x4 __attribute__((ext_vector_type(4)));

#define BQ 32
#define TT 197
#define DD 768
#define HH 12
#define FF 3072
#define LL 12
#define TP 224
#define MR 6304   // B*T
#define MP 6400   // padded to 50*128
#define MQ 75648  // B*T*H rows for qkv gemm (591*128)
#define KST 72    // K LDS row stride (elements)
#define PST 232   // P / Vt LDS row stride (elements)
#define NSPLIT 2  // MLP2 split-K factor

typedef __attribute__((address_space(1))) const void gv_t;
typedef __attribute__((address_space(3))) void lv_t;

__device__ __forceinline__ void gld16(const void* g, void* l) {
    __builtin_amdgcn_global_load_lds((gv_t*)g, (lv_t*)l, 16, 0, 0);
}

__device__ __forceinline__ f32x4 mfma16(bf16x8 a, bf16x8 b, f32x4 c) {
    return __builtin_amdgcn_mfma_f32_16x16x32_bf16(a, b, c, 0, 0, 0);
}

// tanh-approx GELU via hw v_exp_f32; overflow-safe (e=inf -> th=1)
__device__ __forceinline__ float fast_gelu(float v) {
    float t = 0.79788456080286535588f * v * (1.0f + 0.044715f * v * v);
    float e = __expf(2.0f * t);
    float th = 1.0f - 2.0f / (e + 1.0f);
    return 0.5f * v * (1.0f + th);
}

// bijective XCD swizzle (m204): consecutive wgid stay on one XCD
__device__ __forceinline__ int xcd_swz(int bid, int nwg) {
    int q = nwg >> 3, r = nwg & 7;
    int xcd = bid & 7, pos = bid >> 3;
    int base = (xcd < r) ? xcd * (q + 1) : r * (q + 1) + (xcd - r) * q;
    return base + pos;
}

// ---------------------------------------------------------------------------
// C = A(M,K) @ W(N,K)^T GEMM, 128x128 tile, BK=64, 4 waves, single-buffered
// (m97 structure, 32KB LDS -> 3-5 blocks/CU implicit overlap). Column-block
// XOR swizzle (cb ^ row&7) on the global SOURCE side of global_load_lds (LDS
// dest linear, rule #21), mirrored on the ds_read side -> 0 bank conflicts.
// EPI 0: +bias, patch-embed -> h rows (b*197+1+n) += pos_enc (fp32 write)
// EPI 1: +bias, fast GELU -> bf16 out (stride N)
// EPI 2: +bias, direct residual += into fp32 out (stride 768)
// EPI 3: raw partial write -> outF[ks*MP*DD + row*DD + col] (no bias)
// ---------------------------------------------------------------------------
template <int EPI, int SPLITK>
__global__ __launch_bounds__(256, 4)
void gemm_bt(const bf16* __restrict__ A, const bf16* __restrict__ W,
             const float* __restrict__ bias, int K, int N,
             float* __restrict__ outF, bf16* __restrict__ outB,
             const float* __restrict__ pos, int gx, int gy) {
    __shared__ bf16 As[128 * 64];
    __shared__ bf16 Bs[128 * 64];
    const int tid = threadIdx.x;
    const int lane = tid & 63, wave = tid >> 6;
    const int wm = wave >> 1, wn = wave & 1;

    const int wgid = xcd_swz(blockIdx.x, gridDim.x);
    const int ks   = (SPLITK > 1) ? wgid / (gx * gy) : 0;
    const int rem  = (SPLITK > 1) ? wgid % (gx * gy) : wgid;
    const int bx = rem % gx, by = rem / gx;
    const int m0 = by * 128, n0 = bx * 128;

    const int kb = K / SPLITK;
    const int k0 = ks * kb, k1 = k0 + kb;

    f32x4 acc[4][4] = {};
    const bf16* Ab = A + (size_t)m0 * K;
    const bf16* Wb = W + (size_t)n0 * K;

    for (int kt = k0; kt < k1; kt += 64) {
#pragma unroll
        for (int i = 0; i < 4; i++) {
            int idx = i * 256 + tid;
            int row = idx >> 3, cb = idx & 7;
            int gcb = cb ^ (row & 7);   // pre-swizzled source column-block
            gld16(Ab + (size_t)row * K + kt + gcb * 8, As + idx * 8);
            gld16(Wb + (size_t)row * K + kt + gcb * 8, Bs + idx * 8);
        }
        __syncthreads();
        bf16x8 af[4][2], bfr[4][2];
        const int ca = lane >> 4;
#pragma unroll
        for (int f = 0; f < 4; f++) {
            int rowa = wm * 64 + f * 16 + (lane & 15);
            int ma = rowa & 7;
            af[f][0] = *(const bf16x8*)(As + rowa * 64 + ((ca    ) ^ ma) * 8);
            af[f][1] = *(const bf16x8*)(As + rowa * 64 + ((ca + 4) ^ ma) * 8);
            int rowb = wn * 64 + f * 16 + (lane & 15);
            int mb = rowb & 7;
            bfr[f][0] = *(const bf16x8*)(Bs + rowb * 64 + ((ca    ) ^ mb) * 8);
            bfr[f][1] = *(const bf16x8*)(Bs + rowb * 64 + ((ca + 4) ^ mb) * 8);
        }
#pragma unroll
        for (int kh = 0; kh < 2; kh++)
#pragma unroll
            for (int mf = 0; mf < 4; mf++)
#pragma unroll
                for (int nf = 0; nf < 4; nf++)
                    acc[mf][nf] = mfma16(af[mf][kh], bfr[nf][kh], acc[mf][nf]);
        __syncthreads();
    }

    const int r0 = m0 + wm * 64, c0 = n0 + wn * 64;
#pragma unroll
    for (int mf = 0; mf < 4; mf++) {
#pragma unroll
        for (int j = 0; j < 4; j++) {
            int row = r0 + mf * 16 + ((lane >> 4) * 4) + j;
            int pb = 0, pn = 0;
            if (EPI == 0) { pb = row / 196; pn = row - pb * 196; }
#pragma unroll
            for (int nf = 0; nf < 4; nf++) {
                int col = c0 + nf * 16 + (lane & 15);
                float v = acc[mf][nf][j];
                if (EPI == 0) {
                    v += bias[col];
                    float pv = pos[(size_t)(1 + pn) * DD + col];
                    outF[(size_t)(pb * TT + 1 + pn) * DD + col] = v + pv;
                } else if (EPI == 1) {
                    v += bias[col];
                    outB[(size_t)row * N + col] = (bf16)fast_gelu(v);
                } else if (EPI == 2) {
                    v += bias[col];
                    if (row < MR) outF[(size_t)row * DD + col] += v;
                } else {
                    outF[(size_t)(ks * MP + row) * DD + col] = v;
                }
            }
        }
    }
}

// ---------------------------------------------------------------------------
// QKV: A = hn viewed as (B*T*H, 64) contiguous (since D = H*64).
// C (MQ,192) = A @ qkv_w(192,64)^T + qkv_b, scattered to Q/K/V (B*H, 224, 64)
// Same source-side XOR swizzle as gemm_bt.
// ---------------------------------------------------------------------------
__global__ __launch_bounds__(256, 2)
void qkv_kernel(const bf16* __restrict__ hn, const bf16* __restrict__ qw,
                const float* __restrict__ qb, bf16* __restrict__ Q,
                bf16* __restrict__ Kb, bf16* __restrict__ Vb) {
    __shared__ bf16 Asm[128 * 64];
    __shared__ bf16 Wsm[192 * 64];
    const int tid = threadIdx.x, lane = tid & 63, wave = tid >> 6;
    const bf16* Ab = hn + (size_t)blockIdx.x * (128 * 64);
#pragma unroll
    for (int i = 0; i < 4; i++) {
        int idx = i * 256 + tid;
        int row = idx >> 3, cb = idx & 7;
        int gcb = cb ^ (row & 7);
        gld16(Ab + (size_t)row * 64 + gcb * 8, Asm + idx * 8);
    }
#pragma unroll
    for (int i = 0; i < 6; i++) {
        int idx = i * 256 + tid;
        int row = idx >> 3, cb = idx & 7;
        int gcb = cb ^ (row & 7);
        gld16(qw + (size_t)row * 64 + gcb * 8, Wsm + idx * 8);
    }
    __syncthreads();

    const int ca = lane >> 4;
    bf16x8 af[2][2];
#pragma unroll
    for (int mf = 0; mf < 2; mf++) {
        int row = wave * 32 + mf * 16 + (lane & 15);
        int m7 = row & 7;
        af[mf][0] = *(const bf16x8*)(Asm + row * 64 + ((ca    ) ^ m7) * 8);
        af[mf][1] = *(const bf16x8*)(Asm + row * 64 + ((ca + 4) ^ m7) * 8);
    }
    f32x4 acc[2][12] = {};
#pragma unroll
    for (int nf = 0; nf < 12; nf++) {
        int row = nf * 16 + (lane & 15);
        int m7 = row & 7;
        bf16x8 b0 = *(const bf16x8*)(Wsm + row * 64 + ((ca    ) ^ m7) * 8);
        bf16x8 b1 = *(const bf16x8*)(Wsm + row * 64 + ((ca + 4) ^ m7) * 8);
#pragma unroll
        for (int mf = 0; mf < 2; mf++) {
            acc[mf][nf] = mfma16(af[mf][0], b0, acc[mf][nf]);
            acc[mf][nf] = mfma16(af[mf][1], b1, acc[mf][nf]);
        }
    }
    const int r0 = blockIdx.x * 128 + wave * 32;
#pragma unroll
    for (int mf = 0; mf < 2; mf++)
#pragma unroll
        for (int j = 0; j < 4; j++) {
            int r = r0 + mf * 16 + (lane >> 4) * 4 + j;
            int bt = r / 12, hh = r - bt * 12;
            int b = bt / 197, t = bt - b * 197;
            size_t dbase = ((size_t)(b * HH + hh) * TP + t) * 64;
#pragma unroll
            for (int nf = 0; nf < 12; nf++) {
                int col = nf * 16 + (lane & 15);
                float v = acc[mf][nf][j] + qb[col];
                int sel = nf >> 2, e = col & 63;
                bf16* dst = (sel == 0) ? Q : (sel == 1 ? Kb : Vb);
                dst[dbase + e] = (bf16)v;
            }
        }
}

// ---------------------------------------------------------------------------
// Fused attention per (b,h): scores = QK^T*0.125 (masked >=197), softmax,
// O = P@V, h += O (residual). K in LDS [224][72], V transposed [64][232],
// P per-wave [16][232].
// ---------------------------------------------------------------------------
__global__ __launch_bounds__(256, 1)
void attn_kernel(const bf16* __restrict__ Q, const bf16* __restrict__ Kg,
                 const bf16* __restrict__ Vg, float* __restrict__ h) {
    __shared__ bf16 Ks[TP * KST];
    __shared__ bf16 Vt[64 * PST];
    __shared__ bf16 Pw[4 * 16 * PST];
    const int tid = threadIdx.x, lane = tid & 63, wave = tid >> 6;
    const int bh = blockIdx.x;
    const int b = bh / HH, hh = bh - b * HH;
    const bf16* Kp = Kg + (size_t)bh * TP * 64;
    const bf16* Vp = Vg + (size_t)bh * TP * 64;
    const bf16* Qp = Q + (size_t)bh * TP * 64;

#pragma unroll
    for (int i = 0; i < 7; i++) {
        int idx = i * 256 + tid;
        int row = idx >> 3, cb = idx & 7;
        bf16x8 kv = *(const bf16x8*)(Kp + idx * 8);
        *(bf16x8*)(Ks + row * KST + cb * 8) = kv;
        bf16x8 vv = *(const bf16x8*)(Vp + idx * 8);
#pragma unroll
        for (int j = 0; j < 8; j++) Vt[(cb * 8 + j) * PST + row] = vv[j];
    }
    __syncthreads();

    bf16* Pm = Pw + wave * 16 * PST;
    for (int ch = wave; ch < 13; ch += 4) {
        const int q0 = ch * 16;
        const bf16* qp = Qp + (q0 + (lane & 15)) * 64 + (lane >> 4) * 8;
        bf16x8 aq0 = *(const bf16x8*)qp;
        bf16x8 aq1 = *(const bf16x8*)(qp + 32);
        f32x4 s[14] = {};
#pragma unroll
        for (int nf = 0; nf < 14; nf++) {
            int rb = (nf * 16 + (lane & 15)) * KST + (lane >> 4) * 8;
            bf16x8 b0 = *(const bf16x8*)(Ks + rb);
            bf16x8 b1 = *(const bf16x8*)(Ks + rb + 32);
            s[nf] = mfma16(aq0, b0, s[nf]);
            s[nf] = mfma16(aq1, b1, s[nf]);
        }
        const int colbase = lane & 15;
#pragma unroll
        for (int j = 0; j < 4; j++) {
            float pv[14];
            float m = -1e30f;
#pragma unroll
            for (int nf = 0; nf < 14; nf++) {
                int col = nf * 16 + colbase;
                float v = s[nf][j] * 0.125f;
                v = (col < TT) ? v : -1e30f;
                pv[nf] = v;
                m = fmaxf(m, v);
            }
#pragma unroll
            for (int dd = 1; dd < 16; dd <<= 1) m = fmaxf(m, __shfl_xor(m, dd));
            float sum = 0.0f;
#pragma unroll
            for (int nf = 0; nf < 14; nf++) { float e = __expf(pv[nf] - m); pv[nf] = e; sum += e; }
#pragma unroll
            for (int dd = 1; dd < 16; dd <<= 1) sum += __shfl_xor(sum, dd);
            float inv = 1.0f / sum;
            int pr = (lane >> 4) * 4 + j;
#pragma unroll
            for (int nf = 0; nf < 14; nf++)
                Pm[pr * PST + nf * 16 + colbase] = (bf16)(pv[nf] * inv);
        }
        asm volatile("s_waitcnt lgkmcnt(0)" ::: "memory");
        f32x4 o[4] = {};
#pragma unroll
        for (int ks = 0; ks < 7; ks++) {
            bf16x8 pa = *(const bf16x8*)(Pm + (lane & 15) * PST + ks * 32 + (lane >> 4) * 8);
#pragma unroll
            for (int nf = 0; nf < 4; nf++) {
                bf16x8 bv = *(const bf16x8*)(Vt + (nf * 16 + (lane & 15)) * PST + ks * 32 + (lane >> 4) * 8);
                o[nf] = mfma16(pa, bv, o[nf]);
            }
        }
#pragma unroll
        for (int nf = 0; nf < 4; nf++)
#pragma unroll
            for (int j = 0; j < 4; j++) {
                int qr = q0 + (lane >> 4) * 4 + j;
                if (qr < TT) {
                    int d = nf * 16 + (lane & 15);
                    h[(size_t)(b * TT + qr) * DD + hh * 64 + d] += o[nf][j];
                }
            }
    }
}

// ---------------------------------------------------------------------------
// LayerNorm, one row per wave (4 rows/block), fp32 in -> bf16 out
// ---------------------------------------------------------------------------
__device__ __forceinline__ void ln_core(float4 a[3], const float* g, const float* bt,
                                        bf16* hn, int row, int lane) {
    float sum = 0.0f;
#pragma unroll
    for (int i = 0; i < 3; i++) sum += a[i].x + a[i].y + a[i].z + a[i].w;
#pragma unroll
    for (int dd = 1; dd < 64; dd <<= 1) sum += __shfl_xor(sum, dd);
    const float mu = sum * (1.0f / 768.0f);
    float sq = 0.0f;
#pragma unroll
    for (int i = 0; i < 3; i++) {
        float dx = a[i].x - mu, dy = a[i].y - mu, dz = a[i].z - mu, dw = a[i].w - mu;
        sq += dx * dx + dy * dy + dz * dz + dw * dw;
    }
#pragma unroll
    for (int dd = 1; dd < 64; dd <<= 1) sq += __shfl_xor(sq, dd);
    const float is = rsqrtf(sq * (1.0f / 768.0f) + 1e-5f);
#pragma unroll
    for (int i = 0; i < 3; i++) {
        int c4 = lane + i * 64;
        float4 gg = ((const float4*)g)[c4];
        float4 bb = ((const float4*)bt)[c4];
        bf16x4 o;
        o[0] = (bf16)((a[i].x - mu) * is * gg.x + bb.x);
        o[1] = (bf16)((a[i].y - mu) * is * gg.y + bb.y);
        o[2] = (bf16)((a[i].z - mu) * is * gg.z + bb.z);
        o[3] = (bf16)((a[i].w - mu) * is * gg.w + bb.w);
        ((bf16x4*)(hn + (size_t)row * DD))[c4] = o;
    }
}

__global__ void ln_kernel(const float* __restrict__ h, const float* __restrict__ g,
                          const float* __restrict__ bt, bf16* __restrict__ hn) {
    const int lane = threadIdx.x & 63, wave = threadIdx.x >> 6;
    const int row = blockIdx.x * 4 + wave;
    const float* x = h + (size_t)row * DD;
    float4 a[3];
#pragma unroll
    for (int i = 0; i < 3; i++) a[i] = ((const float4*)x)[lane + i * 64];
    ln_core(a, g, bt, hn, row, lane);
}

// h += sum(NS partials) + b2; write h; hn = LN(h)
template <int NS>
__global__ void ln_acc_kernel(float* __restrict__ h, const float* __restrict__ part,
                              const float* __restrict__ b2,
                              const float* __restrict__ g, const float* __restrict__ bt,
                              bf16* __restrict__ hn) {
    const int lane = threadIdx.x & 63, wave = threadIdx.x >> 6;
    const int row = blockIdx.x * 4 + wave;
    float* x = h + (size_t)row * DD;
    float4 a[3];
#pragma unroll
    for (int i = 0; i < 3; i++) a[i] = ((const float4*)x)[lane + i * 64];
#pragma unroll
    for (int s = 0; s < NS; s++) {
        const float4* ps = (const float4*)(part + ((size_t)s * MP + row) * DD);
#pragma unroll
        for (int i = 0; i < 3; i++) {
            float4 p = ps[lane + i * 64];
            a[i].x += p.x; a[i].y += p.y; a[i].z += p.z; a[i].w += p.w;
        }
    }
#pragma unroll
    for (int i = 0; i < 3; i++) {
        float4 bb = ((const float4*)b2)[lane + i * 64];
        a[i].x += bb.x; a[i].y += bb.y; a[i].z += bb.z; a[i].w += bb.w;
        ((float4*)x)[lane + i * 64] = a[i];
    }
    ln_core(a, g, bt, hn, row, lane);
}

// ---------------------------------------------------------------------------
__global__ void patch_extract(const float* __restrict__ x, bf16* __restrict__ p) {
    int idx = blockIdx.x * 256 + threadIdx.x;
    if (idx >= 6272 * 768) return;
    int k = idx % 768, row = idx / 768;
    int c = k % 3, pc = (k / 3) % 16, pr = k / 48;
    int b = row / 196, n = row - b * 196;
    int hp = n / 14, wp = n - hp * 14;
    p[idx] = (bf16)x[((size_t)(b * 3 + c) * 224 + hp * 16 + pr) * 224 + wp * 16 + pc];
}

__global__ void cast_bf16(const float* __restrict__ in, bf16* __restrict__ out, int n4) {
    int i = blockIdx.x * 256 + threadIdx.x;
    int stride = gridDim.x * 256;
    for (; i < n4; i += stride) {
        float4 v = ((const float4*)in)[i];
        bf16x4 o;
        o[0] = (bf16)v.x; o[1] = (bf16)v.y; o[2] = (bf16)v.z; o[3] = (bf16)v.w;
        ((bf16x4*)out)[i] = o;
    }
}

__global__ void cls_init(const float* __restrict__ cls, const float* __restrict__ pos,
                         float* __restrict__ h) {
    int i = blockIdx.x * 256 + threadIdx.x;
    if (i >= BQ * DD) return;
    int b = i / DD, c = i - b * DD;
    h[(size_t)(b * TT) * DD + c] = cls[c] + pos[c];
}

__global__ void head_kernel(const float* __restrict__ h, const float* __restrict__ hw,
                            const float* __restrict__ hb, float* __restrict__ out) {
    __shared__ float xr[DD];
    const int b = blockIdx.y;
    const int n = blockIdx.x * 256 + threadIdx.x;
    for (int i = threadIdx.x; i < DD; i += 256) xr[i] = h[(size_t)(b * TT) * DD + i];
    __syncthreads();
    if (n < 1000) {
        float s = hb[n];
        const float4* w = (const float4*)(hw + (size_t)n * DD);
        float acc = 0.0f;
#pragma unroll 4
        for (int k = 0; k < DD / 4; k++) {
            float4 wv = w[k];
            float4 xv = ((const float4*)xr)[k];
            acc += wv.x * xv.x + wv.y * xv.y + wv.z * xv.z + wv.w * xv.w;
        }
        out[b * 1000 + n] = s + acc;
    }
}

// ---------------------------------------------------------------------------
extern "C" void kernel_launch(void* const* d_in, const int* in_sizes, int n_in,
                              void* d_out, int out_size, void* d_ws, size_t ws_size,
                              hipStream_t stream) {
    const float* x       = (const float*)d_in[0];
    const float* patch_w = (const float*)d_in[1];
    const float* patch_b = (const float*)d_in[2];
    const float* pos_enc = (const float*)d_in[3];
    const float* cls_tok = (const float*)d_in[4];
    const float* qkv_w   = (const float*)d_in[5];
    const float* qkv_b   = (const float*)d_in[6];
    const float* ln_g    = (const float*)d_in[7];
    const float* ln_b    = (const float*)d_in[8];
    const float* w1      = (const float*)d_in[9];
    const float* b1      = (const float*)d_in[10];
    const float* w2      = (const float*)d_in[11];
    const float* b2      = (const float*)d_in[12];
    const float* head_w  = (const float*)d_in[13];
    const float* head_b  = (const float*)d_in[14];

    char* wp = (char*)d_ws;
    auto carve = [&](size_t bytes) {
        char* r = wp;
        wp += (bytes + 255) & ~(size_t)255;
        return r;
    };
    auto fits = [&](size_t bytes) {
        return (size_t)(wp - (char*)d_ws) + bytes + 256 <= ws_size;
    };
    float* h  = (float*)carve((size_t)MP * DD * 4);
    bf16* hn  = (bf16*)carve((size_t)MP * DD * 2);
    bf16* u   = (bf16*)carve((size_t)MP * FF * 2);
    bf16* qs  = (bf16*)carve((size_t)BQ * HH * TP * 64 * 2);
    bf16* ks  = (bf16*)carve((size_t)BQ * HH * TP * 64 * 2);
    bf16* vs  = (bf16*)carve((size_t)BQ * HH * TP * 64 * 2);
    bf16* p   = (bf16*)carve((size_t)6272 * DD * 2);
    bf16* pwb = (bf16*)carve((size_t)DD * DD * 2);
    bf16* qwb = (bf16*)carve((size_t)LL * 192 * 64 * 2);

    // split-K partials (NSPLIT x MP x DD fp32), if ws allows
    float* part = nullptr;
    if (fits((size_t)NSPLIT * MP * DD * 4))
        part = (float*)carve((size_t)NSPLIT * MP * DD * 4);
    const bool use_part = (part != nullptr);

    // precast-all weights, if ws allows
    const size_t wfull = (size_t)LL * FF * DD * 2;
    const bool precast = fits(2 * (wfull + 256));
    bf16* w1b = (bf16*)carve(precast ? wfull : (size_t)FF * DD * 2);
    bf16* w2b = (bf16*)carve(precast ? wfull : (size_t)DD * FF * 2);

    cast_bf16<<<512, 256, 0, stream>>>(patch_w, pwb, (DD * DD) / 4);
    cast_bf16<<<144, 256, 0, stream>>>(qkv_w, qwb, (LL * 192 * 64) / 4);
    if (precast) {
        cast_bf16<<<4096, 256, 0, stream>>>(w1, w1b, (LL * FF * DD) / 4);
        cast_bf16<<<4096, 256, 0, stream>>>(w2, w2b, (LL * FF * DD) / 4);
    }
    patch_extract<<<18816, 256, 0, stream>>>(x, p);
    cls_init<<<96, 256, 0, stream>>>(cls_tok, pos_enc, h);
    gemm_bt<0, 1><<<294, 256, 0, stream>>>(p, pwb, patch_b, 768, 768, h, nullptr,
                                           pos_enc, 6, 49);

    for (int i = 0; i < LL; i++) {
        const bf16* w1i = precast ? (w1b + (size_t)i * FF * DD) : w1b;
        const bf16* w2i = precast ? (w2b + (size_t)i * FF * DD) : w2b;

        // ln1 (fused with previous layer's MLP2 partial reduction + b2 + residual)
        if (use_part && i > 0)
            ln_acc_kernel<NSPLIT><<<MP / 4, 256, 0, stream>>>(h, part, b2 + (i - 1) * DD,
                                                              ln_g + i * DD, ln_b + i * DD, hn);
        else
            ln_kernel<<<MP / 4, 256, 0, stream>>>(h, ln_g + i * DD, ln_b + i * DD, hn);

        qkv_kernel<<<MQ / 128, 256, 0, stream>>>(hn, qwb + i * 192 * 64, qkv_b + i * 192,
                                                 qs, ks, vs);
        attn_kernel<<<BQ * HH, 256, 0, stream>>>(qs, ks, vs, h);
        ln_kernel<<<MP / 4, 256, 0, stream>>>(h, ln_g + i * DD, ln_b + i * DD, hn);
        if (!precast)
            cast_bf16<<<2048, 256, 0, stream>>>(w1 + (size_t)i * FF * DD, w1b, (FF * DD) / 4);
        gemm_bt<1, 1><<<1200, 256, 0, stream>>>(hn, w1i, b1 + i * FF, 768, 3072,
                                                nullptr, u, nullptr, 24, 50);
        if (!precast)
            cast_bf16<<<2048, 256, 0, stream>>>(w2 + (size_t)i * FF * DD, w2b, (FF * DD) / 4);
        if (use_part)
            gemm_bt<3, NSPLIT><<<300 * NSPLIT, 256, 0, stream>>>(u, w2i, nullptr, 3072, 768,
                                                                 part, nullptr, nullptr, 6, 50);
        else
            gemm_bt<2, 1><<<300, 256, 0, stream>>>(u, w2i, b2 + i * DD, 3072, 768,
                                                   h, nullptr, nullptr, 6, 50);
    }
    if (use_part)  // final reduction of layer 11's MLP2 into h (hn output unused)
        ln_acc_kernel<NSPLIT><<<MP / 4, 256, 0, stream>>>(h, part, b2 + 11 * DD,
                                                          ln_g, ln_b, hn);
    head_kernel<<<dim3(4, BQ), 256, 0, stream>>>(h, head_w, head_b, (float*)d_out);
}